// Round 1
// baseline (602.202 us; speedup 1.0000x reference)
//
#include <hip/hip_runtime.h>
#include <hip/hip_bf16.h>

#define B_   4
#define N_   16384
#define T_   65536
#define DIM_ 256
#define H_   8
#define DH_  32
static constexpr float SCALE_F = 0.17677669529663687f; // 32^-0.5

__device__ __forceinline__ unsigned short f2bf(float f) {
    unsigned int u = __float_as_uint(f);
    unsigned int rounding = 0x7fffu + ((u >> 16) & 1u);
    u += rounding;
    return (unsigned short)(u >> 16);
}

// ---------------- K1: fused QKV projection GEMM (f32 compute, bf16 store) ----
// grid = (T/128, 2, 3): z selects {q,k,v}. Tile 128x128, KB=32, 8x8/thread.
__global__ __launch_bounds__(256) void proj_gemm(
    const float* __restrict__ states, const float* __restrict__ agent_qs,
    const float* __restrict__ obs,
    const float* __restrict__ Wq, const float* __restrict__ bq,
    const float* __restrict__ Wk, const float* __restrict__ bk,
    const float* __restrict__ Wv, const float* __restrict__ bv,
    unsigned short* __restrict__ q_bf, unsigned short* __restrict__ k_bf,
    unsigned short* __restrict__ v_bf)
{
    const int m = blockIdx.z;
    const float* X    = (m == 0) ? states : (m == 1) ? agent_qs : obs;
    const float* W    = (m == 0) ? Wq : (m == 1) ? Wk : Wv;
    const float* bias = (m == 0) ? bq : (m == 1) ? bk : bv;
    unsigned short* Y = (m == 0) ? q_bf : (m == 1) ? k_bf : v_bf;

    const int t0 = blockIdx.x * 128;
    const int j0 = blockIdx.y * 128;
    const int tid = threadIdx.x;
    const int tr = tid >> 4, tc = tid & 15;

    __shared__ __align__(16) float As[32][132]; // [k][m], padded (132*4=33*16 keeps rows 16B-aligned)
    __shared__ __align__(16) float Ws[32][128]; // [k][n]

    float acc[8][8];
    #pragma unroll
    for (int i = 0; i < 8; ++i)
        #pragma unroll
        for (int j = 0; j < 8; ++j) acc[i][j] = 0.f;

    for (int k0 = 0; k0 < DIM_; k0 += 32) {
        #pragma unroll
        for (int rep = 0; rep < 4; ++rep) {
            int lin = rep * 256 + tid;
            int row = lin >> 3;   // 0..127 token within tile
            int kg  = lin & 7;    // 0..7, 4 floats each
            float4 a = *reinterpret_cast<const float4*>(
                X + (size_t)(t0 + row) * DIM_ + k0 + kg * 4);
            As[kg*4+0][row] = a.x; As[kg*4+1][row] = a.y;
            As[kg*4+2][row] = a.z; As[kg*4+3][row] = a.w;
        }
        #pragma unroll
        for (int rep = 0; rep < 4; ++rep) {
            int lin = rep * 256 + tid;
            int row = lin >> 5;   // 0..31 k within chunk
            int cg  = lin & 31;   // 0..31, 4 floats each
            *reinterpret_cast<float4*>(&Ws[row][cg*4]) =
                *reinterpret_cast<const float4*>(
                    W + (size_t)(k0 + row) * DIM_ + j0 + cg * 4);
        }
        __syncthreads();
        #pragma unroll 4
        for (int kk = 0; kk < 32; ++kk) {
            float4 a0 = *reinterpret_cast<const float4*>(&As[kk][tr*8]);
            float4 a1 = *reinterpret_cast<const float4*>(&As[kk][tr*8+4]);
            float4 b0 = *reinterpret_cast<const float4*>(&Ws[kk][tc*8]);
            float4 b1 = *reinterpret_cast<const float4*>(&Ws[kk][tc*8+4]);
            float av[8]  = {a0.x,a0.y,a0.z,a0.w,a1.x,a1.y,a1.z,a1.w};
            float bvv[8] = {b0.x,b0.y,b0.z,b0.w,b1.x,b1.y,b1.z,b1.w};
            #pragma unroll
            for (int i = 0; i < 8; ++i)
                #pragma unroll
                for (int j = 0; j < 8; ++j)
                    acc[i][j] = fmaf(av[i], bvv[j], acc[i][j]);
        }
        __syncthreads();
    }

    const bool do_abs = (m == 0);
    #pragma unroll
    for (int i = 0; i < 8; ++i) {
        int t = t0 + tr*8 + i;
        unsigned short h8[8];
        #pragma unroll
        for (int j = 0; j < 8; ++j) {
            float y = acc[i][j] + bias[j0 + tc*8 + j];
            if (do_abs) y = fabsf(y);
            h8[j] = f2bf(y);
        }
        uint4 pk;
        pk.x = (unsigned)h8[0] | ((unsigned)h8[1] << 16);
        pk.y = (unsigned)h8[2] | ((unsigned)h8[3] << 16);
        pk.z = (unsigned)h8[4] | ((unsigned)h8[5] << 16);
        pk.w = (unsigned)h8[6] | ((unsigned)h8[7] << 16);
        *reinterpret_cast<uint4*>(Y + (size_t)t * DIM_ + j0 + tc*8) = pk;
    }
}

// ---------------- K2/K3: softmax pooling over n per (b,h) -------------------
// mode 0: coef = wq_attn*SCALE, data=q  -> gq
// mode 1: coef = gq*wk_attn*SCALE, data=k -> gk
// Logits are O(0.3) by construction, so exp without max-subtraction is exact
// to fp32 (softmax is shift-invariant).
__global__ __launch_bounds__(512) void pool_kernel(
    const unsigned short* __restrict__ data,
    const float* __restrict__ wqa, const float* __restrict__ wka,
    const float* __restrict__ gq_in, float* __restrict__ outv, int mode)
{
    const int bh = blockIdx.x;      // b*8+h, 0..31
    const int b = bh >> 3, h = bh & 7;
    const int tid = threadIdx.x;

    __shared__ float coef[32];
    __shared__ float s_red[8];
    __shared__ float a_red[8][32];

    if (tid < 32) {
        float c = (mode == 0) ? wqa[tid] : gq_in[bh*32 + tid] * wka[tid];
        coef[tid] = c * SCALE_F;
    }
    __syncthreads();
    float cf[32];
    #pragma unroll
    for (int d = 0; d < 32; ++d) cf[d] = coef[d];

    float s = 0.f;
    float acc[32];
    #pragma unroll
    for (int d = 0; d < 32; ++d) acc[d] = 0.f;

    const unsigned short* base = data + (size_t)b * N_ * 256 + h * 32;
    for (int n = tid; n < N_; n += 512) {
        const uint4* p = reinterpret_cast<const uint4*>(base + (size_t)n * 256);
        float qv[32];
        #pragma unroll
        for (int g = 0; g < 4; ++g) {
            uint4 r = p[g];
            unsigned w0 = r.x, w1 = r.y, w2 = r.z, w3 = r.w;
            qv[g*8+0] = __uint_as_float(w0 << 16);
            qv[g*8+1] = __uint_as_float(w0 & 0xffff0000u);
            qv[g*8+2] = __uint_as_float(w1 << 16);
            qv[g*8+3] = __uint_as_float(w1 & 0xffff0000u);
            qv[g*8+4] = __uint_as_float(w2 << 16);
            qv[g*8+5] = __uint_as_float(w2 & 0xffff0000u);
            qv[g*8+6] = __uint_as_float(w3 << 16);
            qv[g*8+7] = __uint_as_float(w3 & 0xffff0000u);
        }
        float l = 0.f;
        #pragma unroll
        for (int d = 0; d < 32; ++d) l = fmaf(qv[d], cf[d], l);
        float e = expf(l);
        s += e;
        #pragma unroll
        for (int d = 0; d < 32; ++d) acc[d] = fmaf(e, qv[d], acc[d]);
    }

    #pragma unroll
    for (int off = 1; off < 64; off <<= 1) {
        s += __shfl_xor(s, off);
        #pragma unroll
        for (int d = 0; d < 32; ++d) acc[d] += __shfl_xor(acc[d], off);
    }
    const int wave = tid >> 6, lane = tid & 63;
    if (lane == 0) {
        s_red[wave] = s;
        #pragma unroll
        for (int d = 0; d < 32; ++d) a_red[wave][d] = acc[d];
    }
    __syncthreads();
    if (tid < 32) {
        float num = 0.f, den = 0.f;
        #pragma unroll
        for (int w2 = 0; w2 < 8; ++w2) { num += a_red[w2][tid]; den += s_red[w2]; }
        outv[bh*32 + tid] = num / den;
    }
}

// ---------------- K3.5: build Wcat[b] = [gk_b ⊙ (BD(Wr)@Wout) ; Wout], c ----
__global__ __launch_bounds__(256) void build_wcat(
    const float* __restrict__ Wr, const float* __restrict__ br,
    const float* __restrict__ Wout, const float* __restrict__ bout,
    const float* __restrict__ gk, float* __restrict__ Wcat,
    float* __restrict__ cvec)
{
    const int i = blockIdx.x;   // 0..511
    const int j = threadIdx.x;  // 0..255
    if (i < 256) {
        const int h = i >> 5, d = i & 31;
        float s = 0.f;
        #pragma unroll 8
        for (int dp = 0; dp < 32; ++dp)
            s = fmaf(Wr[d*32 + dp], Wout[(h*32 + dp)*256 + j], s);
        #pragma unroll
        for (int b = 0; b < 4; ++b)
            Wcat[((size_t)b*512 + i)*256 + j] = gk[(b*8 + h)*32 + d] * s;
    } else {
        const int i2 = i - 256;
        float w = Wout[i2*256 + j];
        #pragma unroll
        for (int b = 0; b < 4; ++b)
            Wcat[((size_t)b*512 + 256 + i2)*256 + j] = w;
        if (i2 == 0) {
            float cj = bout[j];
            for (int r = 0; r < 256; ++r)
                cj = fmaf(br[r & 31], Wout[r*256 + j], cj);
            cvec[j] = cj;
        }
    }
}

// ---------------- K4: out = [v|q] @ Wcat[b] + c  (f32 out) ------------------
__global__ __launch_bounds__(256) void out_gemm(
    const unsigned short* __restrict__ v_bf, const unsigned short* __restrict__ q_bf,
    const float* __restrict__ Wcat, const float* __restrict__ cvec,
    float* __restrict__ out)
{
    const int t0 = blockIdx.x * 128;
    const int j0 = blockIdx.y * 128;
    const int b  = t0 >> 14;            // t0 / N_, tiles never straddle a batch
    const float* Wb = Wcat + (size_t)b * 512 * 256;
    const int tid = threadIdx.x;
    const int tr = tid >> 4, tc = tid & 15;

    __shared__ __align__(16) float As[32][132];
    __shared__ __align__(16) float Ws[32][128];

    float acc[8][8];
    #pragma unroll
    for (int i = 0; i < 8; ++i)
        #pragma unroll
        for (int j = 0; j < 8; ++j) acc[i][j] = 0.f;

    for (int k0 = 0; k0 < 512; k0 += 32) {
        const unsigned short* src = (k0 < 256) ? v_bf : q_bf;
        const int ks = k0 & 255;
        #pragma unroll
        for (int rep = 0; rep < 2; ++rep) {
            int lin = rep * 256 + tid;
            int row = lin >> 2;   // 0..127
            int kg  = lin & 3;    // 0..3, 8 bf16 each
            uint4 r = *reinterpret_cast<const uint4*>(
                src + (size_t)(t0 + row) * 256 + ks + kg * 8);
            unsigned w0 = r.x, w1 = r.y, w2 = r.z, w3 = r.w;
            As[kg*8+0][row] = __uint_as_float(w0 << 16);
            As[kg*8+1][row] = __uint_as_float(w0 & 0xffff0000u);
            As[kg*8+2][row] = __uint_as_float(w1 << 16);
            As[kg*8+3][row] = __uint_as_float(w1 & 0xffff0000u);
            As[kg*8+4][row] = __uint_as_float(w2 << 16);
            As[kg*8+5][row] = __uint_as_float(w2 & 0xffff0000u);
            As[kg*8+6][row] = __uint_as_float(w3 << 16);
            As[kg*8+7][row] = __uint_as_float(w3 & 0xffff0000u);
        }
        #pragma unroll
        for (int rep = 0; rep < 4; ++rep) {
            int lin = rep * 256 + tid;
            int row = lin >> 5;
            int cg  = lin & 31;
            *reinterpret_cast<float4*>(&Ws[row][cg*4]) =
                *reinterpret_cast<const float4*>(
                    Wb + (size_t)(k0 + row) * 256 + j0 + cg * 4);
        }
        __syncthreads();
        #pragma unroll 4
        for (int kk = 0; kk < 32; ++kk) {
            float4 a0 = *reinterpret_cast<const float4*>(&As[kk][tr*8]);
            float4 a1 = *reinterpret_cast<const float4*>(&As[kk][tr*8+4]);
            float4 b0 = *reinterpret_cast<const float4*>(&Ws[kk][tc*8]);
            float4 b1 = *reinterpret_cast<const float4*>(&Ws[kk][tc*8+4]);
            float av[8]  = {a0.x,a0.y,a0.z,a0.w,a1.x,a1.y,a1.z,a1.w};
            float bvv[8] = {b0.x,b0.y,b0.z,b0.w,b1.x,b1.y,b1.z,b1.w};
            #pragma unroll
            for (int i = 0; i < 8; ++i)
                #pragma unroll
                for (int j = 0; j < 8; ++j)
                    acc[i][j] = fmaf(av[i], bvv[j], acc[i][j]);
        }
        __syncthreads();
    }

    #pragma unroll
    for (int i = 0; i < 8; ++i) {
        int t = t0 + tr*8 + i;
        float4 o0, o1;
        o0.x = acc[i][0] + cvec[j0 + tc*8 + 0];
        o0.y = acc[i][1] + cvec[j0 + tc*8 + 1];
        o0.z = acc[i][2] + cvec[j0 + tc*8 + 2];
        o0.w = acc[i][3] + cvec[j0 + tc*8 + 3];
        o1.x = acc[i][4] + cvec[j0 + tc*8 + 4];
        o1.y = acc[i][5] + cvec[j0 + tc*8 + 5];
        o1.z = acc[i][6] + cvec[j0 + tc*8 + 6];
        o1.w = acc[i][7] + cvec[j0 + tc*8 + 7];
        *reinterpret_cast<float4*>(out + (size_t)t * 256 + j0 + tc*8)     = o0;
        *reinterpret_cast<float4*>(out + (size_t)t * 256 + j0 + tc*8 + 4) = o1;
    }
}

extern "C" void kernel_launch(void* const* d_in, const int* in_sizes, int n_in,
                              void* d_out, int out_size, void* d_ws, size_t ws_size,
                              hipStream_t stream)
{
    const float* states   = (const float*)d_in[0];
    const float* agent_qs = (const float*)d_in[1];
    const float* obs      = (const float*)d_in[2];
    const float* Wq   = (const float*)d_in[3];
    const float* bq   = (const float*)d_in[4];
    const float* Wk   = (const float*)d_in[5];
    const float* bk   = (const float*)d_in[6];
    const float* Wv   = (const float*)d_in[7];
    const float* bv   = (const float*)d_in[8];
    const float* wq_attn = (const float*)d_in[9];
    const float* wk_attn = (const float*)d_in[10];
    const float* Wr   = (const float*)d_in[11];
    const float* br   = (const float*)d_in[12];
    const float* Wout = (const float*)d_in[13];
    const float* bout = (const float*)d_in[14];
    float* out = (float*)d_out;

    char* w = (char*)d_ws;
    unsigned short* q_bf = (unsigned short*)w; w += (size_t)T_ * 256 * 2;
    unsigned short* k_bf = (unsigned short*)w; w += (size_t)T_ * 256 * 2;
    unsigned short* v_bf = (unsigned short*)w; w += (size_t)T_ * 256 * 2;
    float* gq   = (float*)w; w += 1024 * sizeof(float);
    float* gk   = (float*)w; w += 1024 * sizeof(float);
    float* Wcat = (float*)w; w += (size_t)4 * 512 * 256 * sizeof(float);
    float* cvec = (float*)w; w += 256 * sizeof(float);

    proj_gemm<<<dim3(T_/128, 2, 3), 256, 0, stream>>>(
        states, agent_qs, obs, Wq, bq, Wk, bk, Wv, bv, q_bf, k_bf, v_bf);
    pool_kernel<<<dim3(32), 512, 0, stream>>>(q_bf, wq_attn, wk_attn, gq, gq, 0);
    pool_kernel<<<dim3(32), 512, 0, stream>>>(k_bf, wq_attn, wk_attn, gq, gk, 1);
    build_wcat<<<dim3(512), 256, 0, stream>>>(Wr, br, Wout, bout, gk, Wcat, cvec);
    out_gemm<<<dim3(T_/128, 2), 256, 0, stream>>>(v_bf, q_bf, Wcat, cvec, out);
}

// Round 2
// 298.086 us; speedup vs baseline: 2.0202x; 2.0202x over previous
//
#include <hip/hip_runtime.h>
#include <hip/hip_bf16.h>

#define B_   4
#define N_   16384
#define T_   65536
#define DIM_ 256
static constexpr float SCALE_F = 0.17677669529663687f; // 32^-0.5

typedef __attribute__((ext_vector_type(8))) short bf16x8;
typedef __attribute__((ext_vector_type(4))) float f32x4;

static __device__ __forceinline__ unsigned pk2bf(float lo, float hi) {
    __hip_bfloat162 t = __float22bfloat162_rn(make_float2(lo, hi));
    union { __hip_bfloat162 h; unsigned u; } c; c.h = t; return c.u;
}
static __device__ __forceinline__ unsigned short f2bf(float f) {
    unsigned u = __float_as_uint(f);
    u += 0x7fffu + ((u >> 16) & 1u);
    return (unsigned short)(u >> 16);
}

// ---------------- prep: Wt_bf[m][n][k] = bf16(W[k][n]), m in {q,k,v} --------
__global__ __launch_bounds__(256) void prep_w(
    const float* __restrict__ Wq, const float* __restrict__ Wk,
    const float* __restrict__ Wv, unsigned short* __restrict__ Wt)
{
    const int m = blockIdx.x;
    const float* W = (m == 0) ? Wq : (m == 1) ? Wk : Wv;
    unsigned short* dst = Wt + (size_t)m * 65536 + (size_t)threadIdx.x * 256;
    #pragma unroll 4
    for (int kb = 0; kb < 32; ++kb) {
        float v[8];
        #pragma unroll
        for (int e = 0; e < 8; ++e) v[e] = W[(kb*8 + e)*256 + threadIdx.x];
        uint4 w;
        w.x = pk2bf(v[0], v[1]); w.y = pk2bf(v[2], v[3]);
        w.z = pk2bf(v[4], v[5]); w.w = pk2bf(v[6], v[7]);
        *reinterpret_cast<uint4*>(dst + kb*8) = w;
    }
}

// ---------------- K1: QKV projection, MFMA bf16 -----------------------------
// grid (2,512,3). 128x128 tile, K=256, 4 waves 2x2, 4x4 frags each.
__global__ __launch_bounds__(256) void proj_mfma(
    const float* __restrict__ states, const float* __restrict__ agent_qs,
    const float* __restrict__ obs, const unsigned short* __restrict__ Wt,
    const float* __restrict__ bq, const float* __restrict__ bk,
    const float* __restrict__ bv,
    unsigned short* __restrict__ q_bf, unsigned short* __restrict__ k_bf,
    unsigned short* __restrict__ v_bf)
{
    __shared__ __align__(16) unsigned short As[2][128*32];
    __shared__ __align__(16) unsigned short Bs[2][128*32];

    const int tid = threadIdx.x;
    // XCD-contiguous bijective remap (nwg=3072, 3072%8==0): keeps the two
    // N-tiles that share an A-panel adjacent on the same XCD.
    const int d = blockIdx.x + (blockIdx.y << 1) + blockIdx.z * 1024;
    const int c = (d & 7) * 384 + (d >> 3);
    const int z  = c >> 10;
    const int rm = c & 1023;
    const int t0 = (rm >> 1) << 7;
    const int j0 = (rm & 1) << 7;

    const float* X = (z == 0) ? states : (z == 1) ? agent_qs : obs;
    const unsigned short* Bt = Wt + (size_t)z * 65536;
    const float* bias = (z == 0) ? bq : (z == 1) ? bk : bv;
    unsigned short* Y = (z == 0) ? q_bf : (z == 1) ? k_bf : v_bf;
    const bool doabs = (z == 0);

    const int srow = tid >> 2, scb = tid & 3;  // staging: 2 reps of (row,chunk)

    const int wid = tid >> 6, lane = tid & 63;
    const int wr = wid >> 1, wc = wid & 1;
    const int l15 = lane & 15, g = lane >> 4;
    const int fs = ((((l15 ^ (l15 >> 2)) & 3) ^ g)) << 4;   // swizzled chunk
    int aoff[4], boff[4];
    #pragma unroll
    for (int i = 0; i < 4; ++i) {
        aoff[i] = ((wr*64 + i*16 + l15) << 6) + fs;
        boff[i] = ((wc*64 + i*16 + l15) << 6) + fs;
    }

    f32x4 acc[4][4];
    #pragma unroll
    for (int mi = 0; mi < 4; ++mi)
        #pragma unroll
        for (int ni = 0; ni < 4; ++ni) acc[mi][ni] = (f32x4){0.f, 0.f, 0.f, 0.f};

    float4 ra0[2], ra1[2];
    uint4 rb[2];

    auto loadAB = [&](int k0) {
        #pragma unroll
        for (int rep = 0; rep < 2; ++rep) {
            const float* s = X + (size_t)(t0 + rep*64 + srow) * 256 + k0 + scb*8;
            ra0[rep] = *reinterpret_cast<const float4*>(s);
            ra1[rep] = *reinterpret_cast<const float4*>(s + 4);
            rb[rep]  = *reinterpret_cast<const uint4*>(
                Bt + (size_t)(j0 + rep*64 + srow) * 256 + k0 + scb*8);
        }
    };
    auto writeAB = [&](int buf) {
        #pragma unroll
        for (int rep = 0; rep < 2; ++rep) {
            int row = rep*64 + srow;
            int off = (row << 6) + ((((row ^ (row >> 2)) & 3) ^ scb) << 4);
            uint4 w;
            w.x = pk2bf(ra0[rep].x, ra0[rep].y); w.y = pk2bf(ra0[rep].z, ra0[rep].w);
            w.z = pk2bf(ra1[rep].x, ra1[rep].y); w.w = pk2bf(ra1[rep].z, ra1[rep].w);
            *reinterpret_cast<uint4*>((char*)&As[buf][0] + off) = w;
            *reinterpret_cast<uint4*>((char*)&Bs[buf][0] + off) = rb[rep];
        }
    };

    loadAB(0);
    writeAB(0);
    __syncthreads();

    int cur = 0;
    for (int step = 0; step < 8; ++step) {
        if (step < 7) loadAB((step + 1) * 32);
        bf16x8 af[4], bfr[4];
        #pragma unroll
        for (int i = 0; i < 4; ++i) {
            af[i]  = *reinterpret_cast<const bf16x8*>((const char*)&As[cur][0] + aoff[i]);
            bfr[i] = *reinterpret_cast<const bf16x8*>((const char*)&Bs[cur][0] + boff[i]);
        }
        #pragma unroll
        for (int mi = 0; mi < 4; ++mi)
            #pragma unroll
            for (int ni = 0; ni < 4; ++ni)
                acc[mi][ni] = __builtin_amdgcn_mfma_f32_16x16x32_bf16(
                    bfr[ni], af[mi], acc[mi][ni], 0, 0, 0);
        if (step < 7) writeAB(cur ^ 1);
        __syncthreads();
        cur ^= 1;
    }

    // D frag (operand-swapped): lane,reg r -> C[m = base+l15][n = base+g*4+r]
    const int colbase = j0 + wc*64 + (g << 2);
    #pragma unroll
    for (int ni = 0; ni < 4; ++ni) {
        float4 bv4 = *reinterpret_cast<const float4*>(bias + colbase + ni*16);
        #pragma unroll
        for (int mi = 0; mi < 4; ++mi) {
            int m = t0 + wr*64 + mi*16 + l15;
            float y0 = acc[mi][ni][0] + bv4.x;
            float y1 = acc[mi][ni][1] + bv4.y;
            float y2 = acc[mi][ni][2] + bv4.z;
            float y3 = acc[mi][ni][3] + bv4.w;
            if (doabs) { y0 = fabsf(y0); y1 = fabsf(y1); y2 = fabsf(y2); y3 = fabsf(y3); }
            uint2 pk;
            pk.x = pk2bf(y0, y1); pk.y = pk2bf(y2, y3);
            *reinterpret_cast<uint2*>(Y + (size_t)m * 256 + colbase + ni*16) = pk;
        }
    }
}

// ---------------- pools: 2-stage softmax pooling -----------------------------
__global__ __launch_bounds__(512) void pool_partial(
    const unsigned short* __restrict__ data,
    const float* __restrict__ wqa, const float* __restrict__ wka,
    const float* __restrict__ gq_in, float* __restrict__ part, int mode)
{
    const int bh = blockIdx.x, ch = blockIdx.y;
    const int b = bh >> 3, h = bh & 7;
    const int tid = threadIdx.x;

    __shared__ float coef[32];
    __shared__ float s_red[8];
    __shared__ float a_red[8][32];

    if (tid < 32) {
        float cc = (mode == 0) ? wqa[tid] : gq_in[bh*32 + tid] * wka[tid];
        coef[tid] = cc * SCALE_F;
    }
    __syncthreads();
    float cf[32];
    #pragma unroll
    for (int d = 0; d < 32; ++d) cf[d] = coef[d];

    float s = 0.f;
    float acc[32];
    #pragma unroll
    for (int d = 0; d < 32; ++d) acc[d] = 0.f;

    const unsigned short* base = data + (size_t)b * N_ * 256 + h * 32;
    for (int n = ch*2048 + tid; n < (ch + 1)*2048; n += 512) {
        const uint4* p = reinterpret_cast<const uint4*>(base + (size_t)n * 256);
        float qv[32];
        #pragma unroll
        for (int gg = 0; gg < 4; ++gg) {
            uint4 r = p[gg];
            unsigned w0 = r.x, w1 = r.y, w2 = r.z, w3 = r.w;
            qv[gg*8+0] = __uint_as_float(w0 << 16);
            qv[gg*8+1] = __uint_as_float(w0 & 0xffff0000u);
            qv[gg*8+2] = __uint_as_float(w1 << 16);
            qv[gg*8+3] = __uint_as_float(w1 & 0xffff0000u);
            qv[gg*8+4] = __uint_as_float(w2 << 16);
            qv[gg*8+5] = __uint_as_float(w2 & 0xffff0000u);
            qv[gg*8+6] = __uint_as_float(w3 << 16);
            qv[gg*8+7] = __uint_as_float(w3 & 0xffff0000u);
        }
        float l = 0.f;
        #pragma unroll
        for (int d = 0; d < 32; ++d) l = fmaf(qv[d], cf[d], l);
        float e = expf(l);
        s += e;
        #pragma unroll
        for (int d = 0; d < 32; ++d) acc[d] = fmaf(e, qv[d], acc[d]);
    }

    #pragma unroll
    for (int off = 1; off < 64; off <<= 1) {
        s += __shfl_xor(s, off);
        #pragma unroll
        for (int d = 0; d < 32; ++d) acc[d] += __shfl_xor(acc[d], off);
    }
    const int wave = tid >> 6, lane = tid & 63;
    if (lane == 0) {
        s_red[wave] = s;
        #pragma unroll
        for (int d = 0; d < 32; ++d) a_red[wave][d] = acc[d];
    }
    __syncthreads();
    if (tid < 32) {
        float num = 0.f, den = 0.f;
        #pragma unroll
        for (int w2 = 0; w2 < 8; ++w2) { num += a_red[w2][tid]; den += s_red[w2]; }
        part[(size_t)(bh*8 + ch)*40 + tid] = num;
        if (tid == 0) part[(size_t)(bh*8 + ch)*40 + 32] = den;
    }
}

__global__ __launch_bounds__(64) void pool_final(
    const float* __restrict__ part, float* __restrict__ outv)
{
    const int bh = blockIdx.x, d = threadIdx.x;
    if (d >= 32) return;
    float num = 0.f, den = 0.f;
    #pragma unroll
    for (int c = 0; c < 8; ++c) {
        num += part[(size_t)(bh*8 + c)*40 + d];
        den += part[(size_t)(bh*8 + c)*40 + 32];
    }
    outv[bh*32 + d] = num / den;
}

// ---------------- S1t[j][i] = sum_dp Wr[i&31][dp]*Wout[(i>>5)*32+dp][j]; cvec
__global__ __launch_bounds__(256) void build_s1(
    const float* __restrict__ Wr, const float* __restrict__ br,
    const float* __restrict__ Wout, const float* __restrict__ bout,
    float* __restrict__ S1t, float* __restrict__ cvec)
{
    const int i = blockIdx.x, j = threadIdx.x;
    if (i < 256) {
        const int h = i >> 5, dd = i & 31;
        float s = 0.f;
        #pragma unroll 8
        for (int dp = 0; dp < 32; ++dp)
            s = fmaf(Wr[dd*32 + dp], Wout[(h*32 + dp)*256 + j], s);
        S1t[(size_t)j*256 + i] = s;
    } else {
        float cj = bout[j];
        for (int r = 0; r < 256; ++r) cj = fmaf(br[r & 31], Wout[r*256 + j], cj);
        cvec[j] = cj;
    }
}

// ---------------- Wcat_t[b][n][k] bf16, k<256: gk*S1, k>=256: Wout ----------
__global__ __launch_bounds__(256) void build_wcat_t(
    const float* __restrict__ gk, const float* __restrict__ S1t,
    const float* __restrict__ Wout, unsigned short* __restrict__ Wcat_t)
{
    const int b = blockIdx.x, n = blockIdx.y, k = threadIdx.x;
    unsigned short* dst = Wcat_t + (size_t)(b*256 + n) * 512;
    dst[k]       = f2bf(gk[b*256 + k] * S1t[(size_t)n*256 + k]);
    dst[k + 256] = f2bf(Wout[(size_t)k*256 + n]);
}

// ---------------- K4: out = [v|q] @ Wcat_t[b]^T + cvec, MFMA bf16 -----------
__global__ __launch_bounds__(256) void out_mfma(
    const unsigned short* __restrict__ v_bf, const unsigned short* __restrict__ q_bf,
    const unsigned short* __restrict__ Wcat_t, const float* __restrict__ cvec,
    float* __restrict__ out)
{
    __shared__ __align__(16) unsigned short As[2][128*32];
    __shared__ __align__(16) unsigned short Bs[2][128*32];

    const int tid = threadIdx.x;
    const int d = blockIdx.x + (blockIdx.y << 1);   // nwg=1024
    const int c = (d & 7) * 128 + (d >> 3);
    const int t0 = (c >> 1) << 7;
    const int j0 = (c & 1) << 7;
    const int b  = t0 >> 14;
    const unsigned short* Bt = Wcat_t + (size_t)b * 256 * 512;

    const int srow = tid >> 2, scb = tid & 3;
    const int wid = tid >> 6, lane = tid & 63;
    const int wr = wid >> 1, wc = wid & 1;
    const int l15 = lane & 15, g = lane >> 4;
    const int fs = ((((l15 ^ (l15 >> 2)) & 3) ^ g)) << 4;
    int aoff[4], boff[4];
    #pragma unroll
    for (int i = 0; i < 4; ++i) {
        aoff[i] = ((wr*64 + i*16 + l15) << 6) + fs;
        boff[i] = ((wc*64 + i*16 + l15) << 6) + fs;
    }

    f32x4 acc[4][4];
    #pragma unroll
    for (int mi = 0; mi < 4; ++mi)
        #pragma unroll
        for (int ni = 0; ni < 4; ++ni) acc[mi][ni] = (f32x4){0.f, 0.f, 0.f, 0.f};

    uint4 ra[2], rb[2];
    auto loadAB = [&](int k0) {
        const unsigned short* src = (k0 < 256) ? v_bf : q_bf;
        const int ks = k0 & 255;
        #pragma unroll
        for (int rep = 0; rep < 2; ++rep) {
            ra[rep] = *reinterpret_cast<const uint4*>(
                src + (size_t)(t0 + rep*64 + srow) * 256 + ks + scb*8);
            rb[rep] = *reinterpret_cast<const uint4*>(
                Bt + (size_t)(j0 + rep*64 + srow) * 512 + k0 + scb*8);
        }
    };
    auto writeAB = [&](int buf) {
        #pragma unroll
        for (int rep = 0; rep < 2; ++rep) {
            int row = rep*64 + srow;
            int off = (row << 6) + ((((row ^ (row >> 2)) & 3) ^ scb) << 4);
            *reinterpret_cast<uint4*>((char*)&As[buf][0] + off) = ra[rep];
            *reinterpret_cast<uint4*>((char*)&Bs[buf][0] + off) = rb[rep];
        }
    };

    loadAB(0);
    writeAB(0);
    __syncthreads();

    int cur = 0;
    for (int step = 0; step < 16; ++step) {
        if (step < 15) loadAB((step + 1) * 32);
        bf16x8 af[4], bfr[4];
        #pragma unroll
        for (int i = 0; i < 4; ++i) {
            af[i]  = *reinterpret_cast<const bf16x8*>((const char*)&As[cur][0] + aoff[i]);
            bfr[i] = *reinterpret_cast<const bf16x8*>((const char*)&Bs[cur][0] + boff[i]);
        }
        #pragma unroll
        for (int mi = 0; mi < 4; ++mi)
            #pragma unroll
            for (int ni = 0; ni < 4; ++ni)
                acc[mi][ni] = __builtin_amdgcn_mfma_f32_16x16x32_bf16(
                    bfr[ni], af[mi], acc[mi][ni], 0, 0, 0);
        if (step < 15) writeAB(cur ^ 1);
        __syncthreads();
        cur ^= 1;
    }

    const int colbase = j0 + wc*64 + (g << 2);
    #pragma unroll
    for (int ni = 0; ni < 4; ++ni) {
        float4 cv = *reinterpret_cast<const float4*>(cvec + colbase + ni*16);
        #pragma unroll
        for (int mi = 0; mi < 4; ++mi) {
            int m = t0 + wr*64 + mi*16 + l15;
            float4 o;
            o.x = acc[mi][ni][0] + cv.x;
            o.y = acc[mi][ni][1] + cv.y;
            o.z = acc[mi][ni][2] + cv.z;
            o.w = acc[mi][ni][3] + cv.w;
            *reinterpret_cast<float4*>(out + (size_t)m * 256 + colbase + ni*16) = o;
        }
    }
}

extern "C" void kernel_launch(void* const* d_in, const int* in_sizes, int n_in,
                              void* d_out, int out_size, void* d_ws, size_t ws_size,
                              hipStream_t stream)
{
    const float* states   = (const float*)d_in[0];
    const float* agent_qs = (const float*)d_in[1];
    const float* obs      = (const float*)d_in[2];
    const float* Wq   = (const float*)d_in[3];
    const float* bq   = (const float*)d_in[4];
    const float* Wk   = (const float*)d_in[5];
    const float* bk   = (const float*)d_in[6];
    const float* Wv   = (const float*)d_in[7];
    const float* bv   = (const float*)d_in[8];
    const float* wq_attn = (const float*)d_in[9];
    const float* wk_attn = (const float*)d_in[10];
    const float* Wr   = (const float*)d_in[11];
    const float* br   = (const float*)d_in[12];
    const float* Wout = (const float*)d_in[13];
    const float* bout = (const float*)d_in[14];
    float* out = (float*)d_out;

    char* w = (char*)d_ws;
    unsigned short* q_bf = (unsigned short*)w; w += (size_t)T_ * 256 * 2;
    unsigned short* k_bf = (unsigned short*)w; w += (size_t)T_ * 256 * 2;
    unsigned short* v_bf = (unsigned short*)w; w += (size_t)T_ * 256 * 2;
    unsigned short* Wt_bf   = (unsigned short*)w; w += (size_t)3 * 65536 * 2;
    unsigned short* Wcat_t  = (unsigned short*)w; w += (size_t)4 * 256 * 512 * 2;
    float* gq   = (float*)w; w += 1024 * sizeof(float);
    float* gk   = (float*)w; w += 1024 * sizeof(float);
    float* part = (float*)w; w += (size_t)256 * 40 * sizeof(float);
    float* S1t  = (float*)w; w += (size_t)256 * 256 * sizeof(float);
    float* cvec = (float*)w; w += 256 * sizeof(float);

    prep_w<<<dim3(3), 256, 0, stream>>>(Wq, Wk, Wv, Wt_bf);
    proj_mfma<<<dim3(2, 512, 3), 256, 0, stream>>>(
        states, agent_qs, obs, Wt_bf, bq, bk, bv, q_bf, k_bf, v_bf);
    pool_partial<<<dim3(32, 8), 512, 0, stream>>>(q_bf, wq_attn, wk_attn, gq, part, 0);
    pool_final<<<dim3(32), 64, 0, stream>>>(part, gq);
    pool_partial<<<dim3(32, 8), 512, 0, stream>>>(k_bf, wq_attn, wk_attn, gq, part, 1);
    pool_final<<<dim3(32), 64, 0, stream>>>(part, gk);
    build_s1<<<dim3(257), 256, 0, stream>>>(Wr, br, Wout, bout, S1t, cvec);
    build_wcat_t<<<dim3(4, 256), 256, 0, stream>>>(gk, S1t, Wout, Wcat_t);
    out_mfma<<<dim3(2, 512), 256, 0, stream>>>(v_bf, q_bf, Wcat_t, cvec, out);
}

// Round 3
// 219.040 us; speedup vs baseline: 2.7493x; 1.3609x over previous
//
#include <hip/hip_runtime.h>
#include <hip/hip_bf16.h>

#define B_   4
#define N_   16384
#define T_   65536
static constexpr float SCALE_F = 0.17677669529663687f; // 32^-0.5

typedef __attribute__((ext_vector_type(8))) short bf16x8;
typedef __attribute__((ext_vector_type(4))) float f32x4;

static __device__ __forceinline__ unsigned pk2bf(float lo, float hi) {
    __hip_bfloat162 t = __float22bfloat162_rn(make_float2(lo, hi));
    union { __hip_bfloat162 h; unsigned u; } c; c.h = t; return c.u;
}
static __device__ __forceinline__ unsigned short f2bf(float f) {
    unsigned u = __float_as_uint(f);
    u += 0x7fffu + ((u >> 16) & 1u);
    return (unsigned short)(u >> 16);
}
// async global->LDS, 16B per lane; dst = wave-uniform base + lane*16
static __device__ __forceinline__ void gl_lds16(const void* g, void* l) {
    __builtin_amdgcn_global_load_lds(
        (const __attribute__((address_space(1))) unsigned int*)g,
        (__attribute__((address_space(3))) unsigned int*)l, 16, 0, 0);
}

// ---------------- prep: Wt_bf[m][n][k] = bf16(W[k][n]) ----------------------
__global__ __launch_bounds__(256) void prep_w(
    const float* __restrict__ Wq, const float* __restrict__ Wk,
    const float* __restrict__ Wv, unsigned short* __restrict__ Wt)
{
    const int m = blockIdx.x;
    const float* W = (m == 0) ? Wq : (m == 1) ? Wk : Wv;
    unsigned short* dst = Wt + (size_t)m * 65536 + (size_t)threadIdx.x * 256;
    #pragma unroll 4
    for (int kb = 0; kb < 32; ++kb) {
        float v[8];
        #pragma unroll
        for (int e = 0; e < 8; ++e) v[e] = W[(kb*8 + e)*256 + threadIdx.x];
        uint4 w;
        w.x = pk2bf(v[0], v[1]); w.y = pk2bf(v[2], v[3]);
        w.z = pk2bf(v[4], v[5]); w.w = pk2bf(v[6], v[7]);
        *reinterpret_cast<uint4*>(dst + kb*8) = w;
    }
}

// ---------------- K1: QKV projection, MFMA bf16 -----------------------------
// grid (1024, 3), 256 thr / 4 waves. Tile 64 M x 256 N, K=256, BK=32.
// A: f32 staged via global_load_lds (src-side XOR swizzle), cvt in reg.
// B: direct global->reg from Wt (L2-resident), col-permuted for 64B stores.
__global__ __launch_bounds__(256) void proj_mfma(
    const float* __restrict__ states, const float* __restrict__ agent_qs,
    const float* __restrict__ obs, const unsigned short* __restrict__ Wt,
    const float* __restrict__ bq, const float* __restrict__ bk,
    const float* __restrict__ bv,
    unsigned short* __restrict__ q_bf, unsigned short* __restrict__ k_bf,
    unsigned short* __restrict__ v_bf)
{
    __shared__ __align__(16) float As[2][64*32];   // [buf][row][32 f32] 16KB

    const int tid = threadIdx.x;
    const int z  = blockIdx.y;
    const int t0 = blockIdx.x * 64;

    const float* X = (z == 0) ? states : (z == 1) ? agent_qs : obs;
    const unsigned short* Bt = Wt + (size_t)z * 65536;
    const float* bias = (z == 0) ? bq : (z == 1) ? bk : bv;
    unsigned short* Y = (z == 0) ? q_bf : (z == 1) ? k_bf : v_bf;
    const bool doabs = (z == 0);

    const int wid = tid >> 6, lane = tid & 63;
    const int l15 = lane & 15, g = lane >> 4;
    const int wc = wid;                      // 4 N-strips of 64

    // column permutation: frag coord n' -> true col c (within 64-strip)
    // c = [n'5][n'3:2][n'4][n'1:0]
    int ntrue[4];
    #pragma unroll
    for (int ni = 0; ni < 4; ++ni) {
        int np = ni*16 + l15;
        int c = (np & 32) | ((np & 12) << 1) | ((np & 16) >> 2) | (np & 3);
        ntrue[ni] = wc*64 + c;
    }

    // staging: 2 instrs/wave, 1KB each; lane -> row base+(lane>>3), chunk lane&7
    const int srow_lane = lane >> 3;
    const int schunk = (lane & 7) ^ (lane >> 3);   // src pre-swizzle (row&7 = lane>>3)
    auto stageA = [&](int buf, int k0) {
        #pragma unroll
        for (int i = 0; i < 2; ++i) {
            int r = (wid*2 + i)*8 + srow_lane;
            const float* src = X + (size_t)(t0 + r)*256 + k0 + schunk*4;
            gl_lds16(src, &As[buf][(wid*2 + i)*256]);
        }
    };
    auto loadB = [&](bf16x8* breg, int k0) {
        #pragma unroll
        for (int ni = 0; ni < 4; ++ni)
            breg[ni] = *reinterpret_cast<const bf16x8*>(
                Bt + (size_t)ntrue[ni]*256 + k0 + g*8);
    };
    auto readA = [&](int buf, bf16x8* areg) {
        #pragma unroll
        for (int mi = 0; mi < 4; ++mi) {
            int m = mi*16 + l15;
            int x = m & 7;
            f32x4 lo = *reinterpret_cast<const f32x4*>(&As[buf][m*32 + ((2*g)  ^x)*4]);
            f32x4 hi = *reinterpret_cast<const f32x4*>(&As[buf][m*32 + ((2*g+1)^x)*4]);
            union { unsigned u[4]; bf16x8 v; } cc;
            cc.u[0] = pk2bf(lo[0], lo[1]);
            cc.u[1] = pk2bf(lo[2], lo[3]);
            cc.u[2] = pk2bf(hi[0], hi[1]);
            cc.u[3] = pk2bf(hi[2], hi[3]);
            areg[mi] = cc.v;
        }
    };

    f32x4 acc[4][4];
    #pragma unroll
    for (int mi = 0; mi < 4; ++mi)
        #pragma unroll
        for (int ni = 0; ni < 4; ++ni) acc[mi][ni] = (f32x4){0.f,0.f,0.f,0.f};

    bf16x8 bcur[4], bnxt[4];
    stageA(0, 0);
    loadB(bcur, 0);
    __syncthreads();

    int cur = 0;
    for (int s = 0; s < 8; ++s) {
        if (s < 7) { stageA(cur ^ 1, (s+1)*32); loadB(bnxt, (s+1)*32); }
        bf16x8 a[4];
        readA(cur, a);
        #pragma unroll
        for (int mi = 0; mi < 4; ++mi)
            #pragma unroll
            for (int ni = 0; ni < 4; ++ni)
                acc[mi][ni] = __builtin_amdgcn_mfma_f32_16x16x32_bf16(
                    bcur[ni], a[mi], acc[mi][ni], 0, 0, 0);
        __syncthreads();
        #pragma unroll
        for (int ni = 0; ni < 4; ++ni) bcur[ni] = bnxt[ni];
        cur ^= 1;
    }

    // epilogue: store s covers true cols wc*64 + s*32 + g*8 + [0,8)
    #pragma unroll
    for (int mi = 0; mi < 4; ++mi) {
        int m = t0 + mi*16 + l15;
        #pragma unroll
        for (int s = 0; s < 2; ++s) {
            int colb = wc*64 + s*32 + g*8;
            float4 b0 = *reinterpret_cast<const float4*>(bias + colb);
            float4 b1 = *reinterpret_cast<const float4*>(bias + colb + 4);
            float y0 = acc[mi][2*s  ][0] + b0.x;
            float y1 = acc[mi][2*s  ][1] + b0.y;
            float y2 = acc[mi][2*s  ][2] + b0.z;
            float y3 = acc[mi][2*s  ][3] + b0.w;
            float y4 = acc[mi][2*s+1][0] + b1.x;
            float y5 = acc[mi][2*s+1][1] + b1.y;
            float y6 = acc[mi][2*s+1][2] + b1.z;
            float y7 = acc[mi][2*s+1][3] + b1.w;
            if (doabs) {
                y0 = fabsf(y0); y1 = fabsf(y1); y2 = fabsf(y2); y3 = fabsf(y3);
                y4 = fabsf(y4); y5 = fabsf(y5); y6 = fabsf(y6); y7 = fabsf(y7);
            }
            uint4 pk;
            pk.x = pk2bf(y0, y1); pk.y = pk2bf(y2, y3);
            pk.z = pk2bf(y4, y5); pk.w = pk2bf(y6, y7);
            *reinterpret_cast<uint4*>(Y + (size_t)m*256 + colb) = pk;
        }
    }
}

// ---------------- pools: 2-stage softmax pooling -----------------------------
__global__ __launch_bounds__(512) void pool_partial(
    const unsigned short* __restrict__ data,
    const float* __restrict__ wqa, const float* __restrict__ wka,
    const float* __restrict__ gq_in, float* __restrict__ part, int mode)
{
    const int bh = blockIdx.x, ch = blockIdx.y;
    const int b = bh >> 3, h = bh & 7;
    const int tid = threadIdx.x;

    __shared__ float coef[32];
    __shared__ float s_red[8];
    __shared__ float a_red[8][32];

    if (tid < 32) {
        float cc = (mode == 0) ? wqa[tid] : gq_in[bh*32 + tid] * wka[tid];
        coef[tid] = cc * SCALE_F;
    }
    __syncthreads();
    float cf[32];
    #pragma unroll
    for (int d = 0; d < 32; ++d) cf[d] = coef[d];

    float s = 0.f;
    float acc[32];
    #pragma unroll
    for (int d = 0; d < 32; ++d) acc[d] = 0.f;

    const unsigned short* base = data + (size_t)b * N_ * 256 + h * 32;
    for (int n = ch*2048 + tid; n < (ch + 1)*2048; n += 512) {
        const uint4* p = reinterpret_cast<const uint4*>(base + (size_t)n * 256);
        float qv[32];
        #pragma unroll
        for (int gg = 0; gg < 4; ++gg) {
            uint4 r = p[gg];
            unsigned w0 = r.x, w1 = r.y, w2 = r.z, w3 = r.w;
            qv[gg*8+0] = __uint_as_float(w0 << 16);
            qv[gg*8+1] = __uint_as_float(w0 & 0xffff0000u);
            qv[gg*8+2] = __uint_as_float(w1 << 16);
            qv[gg*8+3] = __uint_as_float(w1 & 0xffff0000u);
            qv[gg*8+4] = __uint_as_float(w2 << 16);
            qv[gg*8+5] = __uint_as_float(w2 & 0xffff0000u);
            qv[gg*8+6] = __uint_as_float(w3 << 16);
            qv[gg*8+7] = __uint_as_float(w3 & 0xffff0000u);
        }
        float l = 0.f;
        #pragma unroll
        for (int d = 0; d < 32; ++d) l = fmaf(qv[d], cf[d], l);
        float e = expf(l);
        s += e;
        #pragma unroll
        for (int d = 0; d < 32; ++d) acc[d] = fmaf(e, qv[d], acc[d]);
    }

    #pragma unroll
    for (int off = 1; off < 64; off <<= 1) {
        s += __shfl_xor(s, off);
        #pragma unroll
        for (int d = 0; d < 32; ++d) acc[d] += __shfl_xor(acc[d], off);
    }
    const int wave = tid >> 6, lane = tid & 63;
    if (lane == 0) {
        s_red[wave] = s;
        #pragma unroll
        for (int d = 0; d < 32; ++d) a_red[wave][d] = acc[d];
    }
    __syncthreads();
    if (tid < 32) {
        float num = 0.f, den = 0.f;
        #pragma unroll
        for (int w2 = 0; w2 < 8; ++w2) { num += a_red[w2][tid]; den += s_red[w2]; }
        part[(size_t)(bh*8 + ch)*40 + tid] = num;
        if (tid == 0) part[(size_t)(bh*8 + ch)*40 + 32] = den;
    }
}

__global__ __launch_bounds__(64) void pool_final(
    const float* __restrict__ part, float* __restrict__ outv)
{
    const int bh = blockIdx.x, d = threadIdx.x;
    if (d >= 32) return;
    float num = 0.f, den = 0.f;
    #pragma unroll
    for (int c = 0; c < 8; ++c) {
        num += part[(size_t)(bh*8 + c)*40 + d];
        den += part[(size_t)(bh*8 + c)*40 + 32];
    }
    outv[bh*32 + d] = num / den;
}

// ---------------- S1t[j][i] = sum_dp Wr[i&31][dp]*Wout[(i>>5)*32+dp][j]; cvec
__global__ __launch_bounds__(256) void build_s1(
    const float* __restrict__ Wr, const float* __restrict__ br,
    const float* __restrict__ Wout, const float* __restrict__ bout,
    float* __restrict__ S1t, float* __restrict__ cvec)
{
    const int i = blockIdx.x, j = threadIdx.x;
    if (i < 256) {
        const int h = i >> 5, dd = i & 31;
        float s = 0.f;
        #pragma unroll 8
        for (int dp = 0; dp < 32; ++dp)
            s = fmaf(Wr[dd*32 + dp], Wout[(h*32 + dp)*256 + j], s);
        S1t[(size_t)j*256 + i] = s;
    } else {
        float cj = bout[j];
        for (int r = 0; r < 256; ++r) cj = fmaf(br[r & 31], Wout[r*256 + j], cj);
        cvec[j] = cj;
    }
}

// ---------------- Wcat_t[b][n][k] bf16, k<256: gk*S1, k>=256: Wout ----------
__global__ __launch_bounds__(256) void build_wcat_t(
    const float* __restrict__ gk, const float* __restrict__ S1t,
    const float* __restrict__ Wout, unsigned short* __restrict__ Wcat_t)
{
    const int b = blockIdx.x, n = blockIdx.y, k = threadIdx.x;
    unsigned short* dst = Wcat_t + (size_t)(b*256 + n) * 512;
    dst[k]       = f2bf(gk[b*256 + k] * S1t[(size_t)n*256 + k]);
    dst[k + 256] = f2bf(Wout[(size_t)k*256 + n]);
}

// ---------------- K4: out = [v|q] @ Wcat_t[b]^T + cvec ----------------------
// grid (1024), 256 thr / 4 waves. Tile 64 M x 256 N, K=512, BK=32.
__global__ __launch_bounds__(256) void out_mfma(
    const unsigned short* __restrict__ v_bf, const unsigned short* __restrict__ q_bf,
    const unsigned short* __restrict__ Wcat_t, const float* __restrict__ cvec,
    float* __restrict__ out)
{
    __shared__ __align__(16) unsigned short As[2][64*32];  // [buf][row][32 bf16] 8KB

    const int tid = threadIdx.x;
    const int t0 = blockIdx.x * 64;
    const int b  = t0 >> 14;
    const unsigned short* Wb = Wcat_t + (size_t)b * 256 * 512;

    const int wid = tid >> 6, lane = tid & 63;
    const int l15 = lane & 15, g = lane >> 4, wc = wid;

    // staging: 1 instr/wave; lane -> row wid*16+(lane>>2), chunk lane&3
    const int sr = wid*16 + (lane >> 2);
    const int stc = (lane & 3) ^ (sr & 3) ^ ((sr >> 2) & 3);
    auto stageA = [&](int buf, int k0) {
        const unsigned short* src = (k0 < 256) ? v_bf : q_bf;
        int ks = k0 & 255;
        gl_lds16(src + (size_t)(t0 + sr)*256 + ks + stc*8, &As[buf][wid*512]);
    };
    auto loadB = [&](bf16x8* breg, int k0) {
        #pragma unroll
        for (int ni = 0; ni < 4; ++ni) {
            int nt = wc*64 + ni*16 + l15;
            breg[ni] = *reinterpret_cast<const bf16x8*>(
                Wb + (size_t)nt*512 + k0 + g*8);
        }
    };
    auto readA = [&](int buf, bf16x8* areg) {
        #pragma unroll
        for (int mi = 0; mi < 4; ++mi) {
            int m = mi*16 + l15;
            int cc = g ^ (m & 3) ^ ((m >> 2) & 3);
            areg[mi] = *reinterpret_cast<const bf16x8*>(&As[buf][m*32 + cc*8]);
        }
    };

    f32x4 acc[4][4];
    #pragma unroll
    for (int mi = 0; mi < 4; ++mi)
        #pragma unroll
        for (int ni = 0; ni < 4; ++ni) acc[mi][ni] = (f32x4){0.f,0.f,0.f,0.f};

    bf16x8 bcur[4], bnxt[4];
    stageA(0, 0);
    loadB(bcur, 0);
    __syncthreads();

    int cur = 0;
    for (int s = 0; s < 16; ++s) {
        if (s < 15) { stageA(cur ^ 1, (s+1)*32); loadB(bnxt, (s+1)*32); }
        bf16x8 a[4];
        readA(cur, a);
        #pragma unroll
        for (int mi = 0; mi < 4; ++mi)
            #pragma unroll
            for (int ni = 0; ni < 4; ++ni)
                acc[mi][ni] = __builtin_amdgcn_mfma_f32_16x16x32_bf16(
                    bcur[ni], a[mi], acc[mi][ni], 0, 0, 0);
        __syncthreads();
        #pragma unroll
        for (int ni = 0; ni < 4; ++ni) bcur[ni] = bnxt[ni];
        cur ^= 1;
    }

    #pragma unroll
    for (int ni = 0; ni < 4; ++ni) {
        int colb = wc*64 + ni*16 + g*4;
        float4 cv = *reinterpret_cast<const float4*>(cvec + colb);
        #pragma unroll
        for (int mi = 0; mi < 4; ++mi) {
            int m = t0 + mi*16 + l15;
            float4 o;
            o.x = acc[mi][ni][0] + cv.x;
            o.y = acc[mi][ni][1] + cv.y;
            o.z = acc[mi][ni][2] + cv.z;
            o.w = acc[mi][ni][3] + cv.w;
            *reinterpret_cast<float4*>(out + (size_t)m*256 + colb) = o;
        }
    }
}

extern "C" void kernel_launch(void* const* d_in, const int* in_sizes, int n_in,
                              void* d_out, int out_size, void* d_ws, size_t ws_size,
                              hipStream_t stream)
{
    const float* states   = (const float*)d_in[0];
    const float* agent_qs = (const float*)d_in[1];
    const float* obs      = (const float*)d_in[2];
    const float* Wq   = (const float*)d_in[3];
    const float* bq   = (const float*)d_in[4];
    const float* Wk   = (const float*)d_in[5];
    const float* bk   = (const float*)d_in[6];
    const float* Wv   = (const float*)d_in[7];
    const float* bv   = (const float*)d_in[8];
    const float* wq_attn = (const float*)d_in[9];
    const float* wk_attn = (const float*)d_in[10];
    const float* Wr   = (const float*)d_in[11];
    const float* br   = (const float*)d_in[12];
    const float* Wout = (const float*)d_in[13];
    const float* bout = (const float*)d_in[14];
    float* out = (float*)d_out;

    char* w = (char*)d_ws;
    unsigned short* q_bf = (unsigned short*)w; w += (size_t)T_ * 256 * 2;
    unsigned short* k_bf = (unsigned short*)w; w += (size_t)T_ * 256 * 2;
    unsigned short* v_bf = (unsigned short*)w; w += (size_t)T_ * 256 * 2;
    unsigned short* Wt_bf   = (unsigned short*)w; w += (size_t)3 * 65536 * 2;
    unsigned short* Wcat_t  = (unsigned short*)w; w += (size_t)4 * 256 * 512 * 2;
    float* gq   = (float*)w; w += 1024 * sizeof(float);
    float* gk   = (float*)w; w += 1024 * sizeof(float);
    float* part = (float*)w; w += (size_t)256 * 40 * sizeof(float);
    float* S1t  = (float*)w; w += (size_t)256 * 256 * sizeof(float);
    float* cvec = (float*)w; w += 256 * sizeof(float);

    prep_w<<<dim3(3), 256, 0, stream>>>(Wq, Wk, Wv, Wt_bf);
    proj_mfma<<<dim3(1024, 3), 256, 0, stream>>>(
        states, agent_qs, obs, Wt_bf, bq, bk, bv, q_bf, k_bf, v_bf);
    pool_partial<<<dim3(32, 8), 512, 0, stream>>>(q_bf, wq_attn, wk_attn, gq, part, 0);
    pool_final<<<dim3(32), 64, 0, stream>>>(part, gq);
    pool_partial<<<dim3(32, 8), 512, 0, stream>>>(k_bf, wq_attn, wk_attn, gq, part, 1);
    pool_final<<<dim3(32), 64, 0, stream>>>(part, gk);
    build_s1<<<dim3(257), 256, 0, stream>>>(Wr, br, Wout, bout, S1t, cvec);
    build_wcat_t<<<dim3(4, 256), 256, 0, stream>>>(gk, S1t, Wout, Wcat_t);
    out_mfma<<<dim3(1024), 256, 0, stream>>>(v_bf, q_bf, Wcat_t, cvec, out);
}

// Round 4
// 206.088 us; speedup vs baseline: 2.9221x; 1.0628x over previous
//
#include <hip/hip_runtime.h>
#include <hip/hip_bf16.h>

#define B_   4
#define N_   16384
#define T_   65536
static constexpr float SCALE_F = 0.17677669529663687f; // 32^-0.5

typedef __attribute__((ext_vector_type(8))) short bf16x8;
typedef __attribute__((ext_vector_type(4))) float f32x4;

#define BAR() __builtin_amdgcn_s_barrier()
#define WAIT(vm) asm volatile("s_waitcnt vmcnt(" #vm ") lgkmcnt(0)" ::: "memory")

static __device__ __forceinline__ unsigned pk2bf(float lo, float hi) {
    __hip_bfloat162 t = __float22bfloat162_rn(make_float2(lo, hi));
    union { __hip_bfloat162 h; unsigned u; } c; c.h = t; return c.u;
}
static __device__ __forceinline__ unsigned short f2bf(float f) {
    unsigned u = __float_as_uint(f);
    u += 0x7fffu + ((u >> 16) & 1u);
    return (unsigned short)(u >> 16);
}
// async global->LDS, 16B per lane; dst = wave-uniform base + lane*16
static __device__ __forceinline__ void gl_lds16(const void* g, void* l) {
    __builtin_amdgcn_global_load_lds(
        (const __attribute__((address_space(1))) unsigned int*)g,
        (__attribute__((address_space(3))) unsigned int*)l, 16, 0, 0);
}

// ---------------- prep: Wt_bf (3 blocks) + S1t/cvec (257 blocks) ------------
__global__ __launch_bounds__(256) void prep_all(
    const float* __restrict__ Wq, const float* __restrict__ Wk,
    const float* __restrict__ Wv, unsigned short* __restrict__ Wt,
    const float* __restrict__ Wr, const float* __restrict__ br,
    const float* __restrict__ Wout, const float* __restrict__ bout,
    float* __restrict__ S1t, float* __restrict__ cvec)
{
    const int blk = blockIdx.x;
    if (blk < 3) {
        const float* W = (blk == 0) ? Wq : (blk == 1) ? Wk : Wv;
        unsigned short* dst = Wt + (size_t)blk * 65536 + (size_t)threadIdx.x * 256;
        #pragma unroll 4
        for (int kb = 0; kb < 32; ++kb) {
            float v[8];
            #pragma unroll
            for (int e = 0; e < 8; ++e) v[e] = W[(kb*8 + e)*256 + threadIdx.x];
            uint4 w;
            w.x = pk2bf(v[0], v[1]); w.y = pk2bf(v[2], v[3]);
            w.z = pk2bf(v[4], v[5]); w.w = pk2bf(v[6], v[7]);
            *reinterpret_cast<uint4*>(dst + kb*8) = w;
        }
        return;
    }
    const int i = blk - 3, j = threadIdx.x;
    if (i < 256) {
        const int h = i >> 5, dd = i & 31;
        float s = 0.f;
        #pragma unroll 8
        for (int dp = 0; dp < 32; ++dp)
            s = fmaf(Wr[dd*32 + dp], Wout[(h*32 + dp)*256 + j], s);
        S1t[(size_t)j*256 + i] = s;
    } else {
        float cj = bout[j];
        for (int r = 0; r < 256; ++r) cj = fmaf(br[r & 31], Wout[r*256 + j], cj);
        cvec[j] = cj;
    }
}

// ---------------- K1: QKV projection, MFMA bf16, counted-vmcnt pipeline -----
// grid (1024, 3), 256 thr / 4 waves. Tile 64 M x 256 N, K=256, BK=32.
// 3 A-buffers; stage k+2 two steps ahead; raw s_barrier + vmcnt(6).
__global__ __launch_bounds__(256) void proj_mfma(
    const float* __restrict__ states, const float* __restrict__ agent_qs,
    const float* __restrict__ obs, const unsigned short* __restrict__ Wt,
    const float* __restrict__ bq, const float* __restrict__ bk,
    const float* __restrict__ bv,
    unsigned short* __restrict__ q_bf, unsigned short* __restrict__ k_bf,
    unsigned short* __restrict__ v_bf)
{
    __shared__ __align__(16) float As[3][64*32];   // 3 x 8KB

    const int tid = threadIdx.x;
    const int z  = blockIdx.y;
    const int t0 = blockIdx.x * 64;

    const float* X = (z == 0) ? states : (z == 1) ? agent_qs : obs;
    const unsigned short* Bt = Wt + (size_t)z * 65536;
    const float* bias = (z == 0) ? bq : (z == 1) ? bk : bv;
    unsigned short* Y = (z == 0) ? q_bf : (z == 1) ? k_bf : v_bf;
    const bool doabs = (z == 0);

    const int wid = tid >> 6, lane = tid & 63;
    const int l15 = lane & 15, g = lane >> 4;
    const int wc = wid;

    // column permutation: frag coord n' -> true col c = [n'5][n'3:2][n'4][n'1:0]
    int ntrue[4];
    #pragma unroll
    for (int ni = 0; ni < 4; ++ni) {
        int np = ni*16 + l15;
        int c = (np & 32) | ((np & 12) << 1) | ((np & 16) >> 2) | (np & 3);
        ntrue[ni] = wc*64 + c;
    }

    const int srow_lane = lane >> 3;
    const int schunk = (lane & 7) ^ (lane >> 3);   // src pre-swizzle
    auto stageA = [&](int buf, int step) {
        const int k0 = step * 32;
        #pragma unroll
        for (int i = 0; i < 2; ++i) {
            int r = (wid*2 + i)*8 + srow_lane;
            gl_lds16(X + (size_t)(t0 + r)*256 + k0 + schunk*4,
                     &As[buf][(wid*2 + i)*256]);
        }
    };
    auto loadB = [&](bf16x8* breg, int step) {
        const int k0 = step * 32;
        #pragma unroll
        for (int ni = 0; ni < 4; ++ni)
            breg[ni] = *reinterpret_cast<const bf16x8*>(
                Bt + (size_t)ntrue[ni]*256 + k0 + g*8);
    };
    auto dsreadA = [&](int buf, f32x4* lo, f32x4* hi) {
        #pragma unroll
        for (int mi = 0; mi < 4; ++mi) {
            int m = mi*16 + l15;
            int x = m & 7;
            lo[mi] = *reinterpret_cast<const f32x4*>(&As[buf][m*32 + ((2*g)  ^x)*4]);
            hi[mi] = *reinterpret_cast<const f32x4*>(&As[buf][m*32 + ((2*g+1)^x)*4]);
        }
    };

    f32x4 acc[4][4];
    #pragma unroll
    for (int mi = 0; mi < 4; ++mi)
        #pragma unroll
        for (int ni = 0; ni < 4; ++ni) acc[mi][ni] = (f32x4){0.f,0.f,0.f,0.f};

    auto mfma_step = [&](const bf16x8* bb, const f32x4* lo, const f32x4* hi) {
        bf16x8 a[4];
        #pragma unroll
        for (int mi = 0; mi < 4; ++mi) {
            union { unsigned u[4]; bf16x8 v; } cc;
            cc.u[0] = pk2bf(lo[mi][0], lo[mi][1]);
            cc.u[1] = pk2bf(lo[mi][2], lo[mi][3]);
            cc.u[2] = pk2bf(hi[mi][0], hi[mi][1]);
            cc.u[3] = pk2bf(hi[mi][2], hi[mi][3]);
            a[mi] = cc.v;
        }
        #pragma unroll
        for (int mi = 0; mi < 4; ++mi)
            #pragma unroll
            for (int ni = 0; ni < 4; ++ni)
                acc[mi][ni] = __builtin_amdgcn_mfma_f32_16x16x32_bf16(
                    bb[ni], a[mi], acc[mi][ni], 0, 0, 0);
    };

    bf16x8 bcur[4], bn[4];
    loadB(bcur, 0);
    stageA(0, 0);
    stageA(1, 1);
    WAIT(0); BAR();

    int br_ = 0, bw_ = 2;
    for (int s = 0; s < 6; ++s) {
        loadB(bn, s + 1);
        f32x4 lo[4], hi[4];
        dsreadA(br_, lo, hi);
        stageA(bw_, s + 2);
        mfma_step(bcur, lo, hi);
        WAIT(6); BAR();
        #pragma unroll
        for (int ni = 0; ni < 4; ++ni) bcur[ni] = bn[ni];
        br_ = (br_ == 2) ? 0 : br_ + 1;
        bw_ = (bw_ == 2) ? 0 : bw_ + 1;
    }
    {   // s = 6 (no stage: k=8 doesn't exist)
        loadB(bn, 7);
        f32x4 lo[4], hi[4];
        dsreadA(br_, lo, hi);
        mfma_step(bcur, lo, hi);
        WAIT(4); BAR();
        #pragma unroll
        for (int ni = 0; ni < 4; ++ni) bcur[ni] = bn[ni];
        br_ = (br_ == 2) ? 0 : br_ + 1;
    }
    {   // s = 7
        f32x4 lo[4], hi[4];
        dsreadA(br_, lo, hi);
        mfma_step(bcur, lo, hi);
    }

    // epilogue: store s covers true cols wc*64 + s*32 + g*8 + [0,8)
    #pragma unroll
    for (int s = 0; s < 2; ++s) {
        int colb = wc*64 + s*32 + g*8;
        float4 b0 = *reinterpret_cast<const float4*>(bias + colb);
        float4 b1 = *reinterpret_cast<const float4*>(bias + colb + 4);
        #pragma unroll
        for (int mi = 0; mi < 4; ++mi) {
            int m = t0 + mi*16 + l15;
            float y0 = acc[mi][2*s  ][0] + b0.x;
            float y1 = acc[mi][2*s  ][1] + b0.y;
            float y2 = acc[mi][2*s  ][2] + b0.z;
            float y3 = acc[mi][2*s  ][3] + b0.w;
            float y4 = acc[mi][2*s+1][0] + b1.x;
            float y5 = acc[mi][2*s+1][1] + b1.y;
            float y6 = acc[mi][2*s+1][2] + b1.z;
            float y7 = acc[mi][2*s+1][3] + b1.w;
            if (doabs) {
                y0 = fabsf(y0); y1 = fabsf(y1); y2 = fabsf(y2); y3 = fabsf(y3);
                y4 = fabsf(y4); y5 = fabsf(y5); y6 = fabsf(y6); y7 = fabsf(y7);
            }
            uint4 pk;
            pk.x = pk2bf(y0, y1); pk.y = pk2bf(y2, y3);
            pk.z = pk2bf(y4, y5); pk.w = pk2bf(y6, y7);
            *reinterpret_cast<uint4*>(Y + (size_t)m*256 + colb) = pk;
        }
    }
}

// ---------------- pools: partial softmax pooling ----------------------------
// mode 0: coef = wqa*SCALE. mode 1: compute gq from part_in, coef = gq*wka*SCALE.
__global__ __launch_bounds__(512) void pool_partial(
    const unsigned short* __restrict__ data,
    const float* __restrict__ wqa, const float* __restrict__ wka,
    const float* __restrict__ part_in, float* __restrict__ part_out, int mode)
{
    const int bh = blockIdx.x, ch = blockIdx.y;
    const int b = bh >> 3, h = bh & 7;
    const int tid = threadIdx.x;

    __shared__ float coef[32];
    __shared__ float s_red[8];
    __shared__ float a_red[8][32];

    if (tid < 32) {
        float cc;
        if (mode == 0) cc = wqa[tid];
        else {
            float num = 0.f, den = 0.f;
            #pragma unroll
            for (int c = 0; c < 8; ++c) {
                num += part_in[(size_t)(bh*8 + c)*40 + tid];
                den += part_in[(size_t)(bh*8 + c)*40 + 32];
            }
            cc = (num / den) * wka[tid];
        }
        coef[tid] = cc * SCALE_F;
    }
    __syncthreads();
    float cf[32];
    #pragma unroll
    for (int d = 0; d < 32; ++d) cf[d] = coef[d];

    float s = 0.f;
    float acc[32];
    #pragma unroll
    for (int d = 0; d < 32; ++d) acc[d] = 0.f;

    const unsigned short* base = data + (size_t)b * N_ * 256 + h * 32;
    for (int n = ch*2048 + tid; n < (ch + 1)*2048; n += 512) {
        const uint4* p = reinterpret_cast<const uint4*>(base + (size_t)n * 256);
        float qv[32];
        #pragma unroll
        for (int gg = 0; gg < 4; ++gg) {
            uint4 r = p[gg];
            unsigned w0 = r.x, w1 = r.y, w2 = r.z, w3 = r.w;
            qv[gg*8+0] = __uint_as_float(w0 << 16);
            qv[gg*8+1] = __uint_as_float(w0 & 0xffff0000u);
            qv[gg*8+2] = __uint_as_float(w1 << 16);
            qv[gg*8+3] = __uint_as_float(w1 & 0xffff0000u);
            qv[gg*8+4] = __uint_as_float(w2 << 16);
            qv[gg*8+5] = __uint_as_float(w2 & 0xffff0000u);
            qv[gg*8+6] = __uint_as_float(w3 << 16);
            qv[gg*8+7] = __uint_as_float(w3 & 0xffff0000u);
        }
        float l = 0.f;
        #pragma unroll
        for (int d = 0; d < 32; ++d) l = fmaf(qv[d], cf[d], l);
        float e = expf(l);
        s += e;
        #pragma unroll
        for (int d = 0; d < 32; ++d) acc[d] = fmaf(e, qv[d], acc[d]);
    }

    #pragma unroll
    for (int off = 1; off < 64; off <<= 1) {
        s += __shfl_xor(s, off);
        #pragma unroll
        for (int d = 0; d < 32; ++d) acc[d] += __shfl_xor(acc[d], off);
    }
    const int wave = tid >> 6, lane = tid & 63;
    if (lane == 0) {
        s_red[wave] = s;
        #pragma unroll
        for (int d = 0; d < 32; ++d) a_red[wave][d] = acc[d];
    }
    __syncthreads();
    if (tid < 32) {
        float num = 0.f, den = 0.f;
        #pragma unroll
        for (int w2 = 0; w2 < 8; ++w2) { num += a_red[w2][tid]; den += s_red[w2]; }
        part_out[(size_t)(bh*8 + ch)*40 + tid] = num;
        if (tid == 0) part_out[(size_t)(bh*8 + ch)*40 + 32] = den;
    }
}

// ---------------- Wcat_t[b][n][k] bf16 (gk computed inline from part_k) -----
__global__ __launch_bounds__(256) void build_wcat_t(
    const float* __restrict__ part_k, const float* __restrict__ S1t,
    const float* __restrict__ Wout, unsigned short* __restrict__ Wcat_t)
{
    const int b = blockIdx.x, n = blockIdx.y, k = threadIdx.x;
    const int h = k >> 5, d = k & 31;
    float num = 0.f, den = 0.f;
    #pragma unroll
    for (int c = 0; c < 8; ++c) {
        num += part_k[(size_t)((b*8 + h)*8 + c)*40 + d];
        den += part_k[(size_t)((b*8 + h)*8 + c)*40 + 32];
    }
    const float gkv = num / den;
    unsigned short* dst = Wcat_t + (size_t)(b*256 + n) * 512;
    dst[k]       = f2bf(gkv * S1t[(size_t)n*256 + k]);
    dst[k + 256] = f2bf(Wout[(size_t)k*256 + n]);
}

// ---------------- K4: out = [v|q] @ Wcat_t[b]^T + cvec, counted-vmcnt -------
// grid (1024), 256 thr / 4 waves. Tile 64 M x 256 N, K=512, BK=32, 16 steps.
__global__ __launch_bounds__(256) void out_mfma(
    const unsigned short* __restrict__ v_bf, const unsigned short* __restrict__ q_bf,
    const unsigned short* __restrict__ Wcat_t, const float* __restrict__ cvec,
    float* __restrict__ out)
{
    __shared__ __align__(16) unsigned short As[3][64*32];  // 3 x 4KB

    const int tid = threadIdx.x;
    const int t0 = blockIdx.x * 64;
    const int b  = t0 >> 14;
    const unsigned short* Wb = Wcat_t + (size_t)b * 256 * 512;

    const int wid = tid >> 6, lane = tid & 63;
    const int l15 = lane & 15, g = lane >> 4, wc = wid;

    const int sr = wid*16 + (lane >> 2);
    const int stc = (lane & 3) ^ (sr & 3) ^ ((sr >> 2) & 3);
    auto stageA = [&](int buf, int step) {
        const int k0 = step * 32;
        const unsigned short* src = (k0 < 256) ? v_bf : q_bf;
        int ks = k0 & 255;
        gl_lds16(src + (size_t)(t0 + sr)*256 + ks + stc*8, &As[buf][wid*512]);
    };
    auto loadB = [&](bf16x8* breg, int step) {
        const int k0 = step * 32;
        #pragma unroll
        for (int ni = 0; ni < 4; ++ni) {
            int nt = wc*64 + ni*16 + l15;
            breg[ni] = *reinterpret_cast<const bf16x8*>(
                Wb + (size_t)nt*512 + k0 + g*8);
        }
    };

    f32x4 acc[4][4];
    #pragma unroll
    for (int mi = 0; mi < 4; ++mi)
        #pragma unroll
        for (int ni = 0; ni < 4; ++ni) acc[mi][ni] = (f32x4){0.f,0.f,0.f,0.f};

    auto step_body = [&](int buf, const bf16x8* bb) {
        bf16x8 a[4];
        #pragma unroll
        for (int mi = 0; mi < 4; ++mi) {
            int m = mi*16 + l15;
            int cc = g ^ (m & 3) ^ ((m >> 2) & 3);
            a[mi] = *reinterpret_cast<const bf16x8*>(&As[buf][m*32 + cc*8]);
        }
        #pragma unroll
        for (int mi = 0; mi < 4; ++mi)
            #pragma unroll
            for (int ni = 0; ni < 4; ++ni)
                acc[mi][ni] = __builtin_amdgcn_mfma_f32_16x16x32_bf16(
                    bb[ni], a[mi], acc[mi][ni], 0, 0, 0);
    };

    bf16x8 bcur[4], bn[4];
    loadB(bcur, 0);
    stageA(0, 0);
    stageA(1, 1);
    WAIT(0); BAR();

    int br_ = 0, bw_ = 2;
    for (int s = 0; s < 14; ++s) {
        loadB(bn, s + 1);
        stageA(bw_, s + 2);
        step_body(br_, bcur);
        WAIT(5); BAR();
        #pragma unroll
        for (int ni = 0; ni < 4; ++ni) bcur[ni] = bn[ni];
        br_ = (br_ == 2) ? 0 : br_ + 1;
        bw_ = (bw_ == 2) ? 0 : bw_ + 1;
    }
    {   // s = 14
        loadB(bn, 15);
        step_body(br_, bcur);
        WAIT(4); BAR();
        #pragma unroll
        for (int ni = 0; ni < 4; ++ni) bcur[ni] = bn[ni];
        br_ = (br_ == 2) ? 0 : br_ + 1;
    }
    step_body(br_, bcur);   // s = 15

    #pragma unroll
    for (int ni = 0; ni < 4; ++ni) {
        int colb = wc*64 + ni*16 + g*4;
        float4 cv = *reinterpret_cast<const float4*>(cvec + colb);
        #pragma unroll
        for (int mi = 0; mi < 4; ++mi) {
            int m = t0 + mi*16 + l15;
            float4 o;
            o.x = acc[mi][ni][0] + cv.x;
            o.y = acc[mi][ni][1] + cv.y;
            o.z = acc[mi][ni][2] + cv.z;
            o.w = acc[mi][ni][3] + cv.w;
            *reinterpret_cast<float4*>(out + (size_t)m*256 + colb) = o;
        }
    }
}

extern "C" void kernel_launch(void* const* d_in, const int* in_sizes, int n_in,
                              void* d_out, int out_size, void* d_ws, size_t ws_size,
                              hipStream_t stream)
{
    const float* states   = (const float*)d_in[0];
    const float* agent_qs = (const float*)d_in[1];
    const float* obs      = (const float*)d_in[2];
    const float* Wq   = (const float*)d_in[3];
    const float* bq   = (const float*)d_in[4];
    const float* Wk   = (const float*)d_in[5];
    const float* bk   = (const float*)d_in[6];
    const float* Wv   = (const float*)d_in[7];
    const float* bv   = (const float*)d_in[8];
    const float* wq_attn = (const float*)d_in[9];
    const float* wk_attn = (const float*)d_in[10];
    const float* Wr   = (const float*)d_in[11];
    const float* br   = (const float*)d_in[12];
    const float* Wout = (const float*)d_in[13];
    const float* bout = (const float*)d_in[14];
    float* out = (float*)d_out;

    char* w = (char*)d_ws;
    unsigned short* q_bf = (unsigned short*)w; w += (size_t)T_ * 256 * 2;
    unsigned short* k_bf = (unsigned short*)w; w += (size_t)T_ * 256 * 2;
    unsigned short* v_bf = (unsigned short*)w; w += (size_t)T_ * 256 * 2;
    unsigned short* Wt_bf   = (unsigned short*)w; w += (size_t)3 * 65536 * 2;
    unsigned short* Wcat_t  = (unsigned short*)w; w += (size_t)4 * 256 * 512 * 2;
    float* part_q = (float*)w; w += (size_t)256 * 40 * sizeof(float);
    float* part_k = (float*)w; w += (size_t)256 * 40 * sizeof(float);
    float* S1t  = (float*)w; w += (size_t)256 * 256 * sizeof(float);
    float* cvec = (float*)w; w += 256 * sizeof(float);

    prep_all<<<dim3(260), 256, 0, stream>>>(Wq, Wk, Wv, Wt_bf,
                                            Wr, br, Wout, bout, S1t, cvec);
    proj_mfma<<<dim3(1024, 3), 256, 0, stream>>>(
        states, agent_qs, obs, Wt_bf, bq, bk, bv, q_bf, k_bf, v_bf);
    pool_partial<<<dim3(32, 8), 512, 0, stream>>>(q_bf, wq_attn, wk_attn,
                                                  part_q, part_q, 0);
    pool_partial<<<dim3(32, 8), 512, 0, stream>>>(k_bf, wq_attn, wk_attn,
                                                  part_q, part_k, 1);
    build_wcat_t<<<dim3(4, 256), 256, 0, stream>>>(part_k, S1t, Wout, Wcat_t);
    out_mfma<<<dim3(1024), 256, 0, stream>>>(v_bf, q_bf, Wcat_t, cvec, out);
}

// Round 5
// 200.291 us; speedup vs baseline: 3.0066x; 1.0289x over previous
//
#include <hip/hip_runtime.h>
#include <hip/hip_bf16.h>

#define B_   4
#define N_   16384
#define T_   65536
static constexpr float SCALE_F = 0.17677669529663687f; // 32^-0.5

typedef __attribute__((ext_vector_type(8))) short bf16x8;
typedef __attribute__((ext_vector_type(4))) float f32x4;

#define BAR() __builtin_amdgcn_s_barrier()
#define WAIT(vm) asm volatile("s_waitcnt vmcnt(" #vm ") lgkmcnt(0)" ::: "memory")

static __device__ __forceinline__ unsigned pk2bf(float lo, float hi) {
    __hip_bfloat162 t = __float22bfloat162_rn(make_float2(lo, hi));
    union { __hip_bfloat162 h; unsigned u; } c; c.h = t; return c.u;
}
static __device__ __forceinline__ unsigned short f2bf(float f) {
    unsigned u = __float_as_uint(f);
    u += 0x7fffu + ((u >> 16) & 1u);
    return (unsigned short)(u >> 16);
}
// async global->LDS, 16B per lane; dst = wave-uniform base + lane*16
static __device__ __forceinline__ void gl_lds16(const void* g, void* l) {
    __builtin_amdgcn_global_load_lds(
        (const __attribute__((address_space(1))) unsigned int*)g,
        (__attribute__((address_space(3))) unsigned int*)l, 16, 0, 0);
}

// ---------------- prep: Wt_bf (3 blocks) + S1t/cvec (257 blocks) ------------
__global__ __launch_bounds__(256) void prep_all(
    const float* __restrict__ Wq, const float* __restrict__ Wk,
    const float* __restrict__ Wv, unsigned short* __restrict__ Wt,
    const float* __restrict__ Wr, const float* __restrict__ br,
    const float* __restrict__ Wout, const float* __restrict__ bout,
    float* __restrict__ S1t, float* __restrict__ cvec)
{
    const int blk = blockIdx.x;
    if (blk < 3) {
        const float* W = (blk == 0) ? Wq : (blk == 1) ? Wk : Wv;
        unsigned short* dst = Wt + (size_t)blk * 65536 + (size_t)threadIdx.x * 256;
        #pragma unroll 4
        for (int kb = 0; kb < 32; ++kb) {
            float v[8];
            #pragma unroll
            for (int e = 0; e < 8; ++e) v[e] = W[(kb*8 + e)*256 + threadIdx.x];
            uint4 w;
            w.x = pk2bf(v[0], v[1]); w.y = pk2bf(v[2], v[3]);
            w.z = pk2bf(v[4], v[5]); w.w = pk2bf(v[6], v[7]);
            *reinterpret_cast<uint4*>(dst + kb*8) = w;
        }
        return;
    }
    const int i = blk - 3, j = threadIdx.x;
    if (i < 256) {
        const int h = i >> 5, dd = i & 31;
        float s = 0.f;
        #pragma unroll 8
        for (int dp = 0; dp < 32; ++dp)
            s = fmaf(Wr[dd*32 + dp], Wout[(h*32 + dp)*256 + j], s);
        S1t[(size_t)j*256 + i] = s;
    } else {
        float cj = bout[j];
        for (int r = 0; r < 256; ++r) cj = fmaf(br[r & 31], Wout[r*256 + j], cj);
        cvec[j] = cj;
    }
}

// ---------------- K1: QKV projection, MFMA bf16, A+B via global_load_lds ----
// grid (1024, 3), 256 thr / 4 waves. Tile 64 M x 256 N, K=256, BK=32.
// 3 buffers; stage step s+2 two steps ahead; counted vmcnt(6) across barriers.
__global__ __launch_bounds__(256) void proj_mfma(
    const float* __restrict__ states, const float* __restrict__ agent_qs,
    const float* __restrict__ obs, const unsigned short* __restrict__ Wt,
    const float* __restrict__ bq, const float* __restrict__ bk,
    const float* __restrict__ bv,
    unsigned short* __restrict__ q_bf, unsigned short* __restrict__ k_bf,
    unsigned short* __restrict__ v_bf)
{
    __shared__ __align__(16) float          As[3][64*32];   // 3 x 8KB
    __shared__ __align__(16) unsigned short Bs[3][256*32];  // 3 x 16KB

    const int tid = threadIdx.x;
    const int z  = blockIdx.y;
    const int t0 = blockIdx.x * 64;

    const float* X = (z == 0) ? states : (z == 1) ? agent_qs : obs;
    const unsigned short* Bt = Wt + (size_t)z * 65536;
    const float* bias = (z == 0) ? bq : (z == 1) ? bk : bv;
    unsigned short* Y = (z == 0) ? q_bf : (z == 1) ? k_bf : v_bf;
    const bool doabs = (z == 0);

    const int wid = tid >> 6, lane = tid & 63;
    const int l15 = lane & 15, g = lane >> 4;
    const int wc = wid;

    // column permutation: frag coord n' -> true col c = [n'5][n'3:2][n'4][n'1:0]
    int ntrue[4];
    #pragma unroll
    for (int ni = 0; ni < 4; ++ni) {
        int np = ni*16 + l15;
        int c = (np & 32) | ((np & 12) << 1) | ((np & 16) >> 2) | (np & 3);
        ntrue[ni] = wc*64 + c;
    }

    // A staging (2 ops/wave): row = base + lane>>3, f32 chunk16 = (lane&7)^row&7
    const int srow_lane = lane >> 3;
    const int schunk = (lane & 7) ^ (lane >> 3);
    // B staging (4 ops/wave): row n = base + lane>>2, slot = lane&3, src
    // chunk = slot ^ (n&3) ^ ((n>>2)&3)  (pre-swizzled source, linear LDS)
    auto stage = [&](int buf, int step) {
        const int k0 = step * 32;
        #pragma unroll
        for (int j = 0; j < 4; ++j) {
            int n = wid*64 + j*16 + (lane >> 2);
            int cs = (lane & 3) ^ (n & 3) ^ ((n >> 2) & 3);
            gl_lds16(Bt + (size_t)n*256 + k0 + cs*8,
                     &Bs[buf][(wid*64 + j*16)*32]);
        }
        #pragma unroll
        for (int i = 0; i < 2; ++i) {
            int r = (wid*2 + i)*8 + srow_lane;
            gl_lds16(X + (size_t)(t0 + r)*256 + k0 + schunk*4,
                     &As[buf][(wid*2 + i)*256]);
        }
    };
    auto dsreadB = [&](int buf, bf16x8* bb) {
        #pragma unroll
        for (int ni = 0; ni < 4; ++ni) {
            int n2 = ntrue[ni];
            int slot = g ^ (n2 & 3) ^ ((n2 >> 2) & 3);
            bb[ni] = *reinterpret_cast<const bf16x8*>(&Bs[buf][n2*32 + slot*8]);
        }
    };
    auto dsreadA = [&](int buf, f32x4* lo, f32x4* hi) {
        #pragma unroll
        for (int mi = 0; mi < 4; ++mi) {
            int m = mi*16 + l15;
            int x = m & 7;
            lo[mi] = *reinterpret_cast<const f32x4*>(&As[buf][m*32 + ((2*g)  ^x)*4]);
            hi[mi] = *reinterpret_cast<const f32x4*>(&As[buf][m*32 + ((2*g+1)^x)*4]);
        }
    };

    f32x4 acc[4][4];
    #pragma unroll
    for (int mi = 0; mi < 4; ++mi)
        #pragma unroll
        for (int ni = 0; ni < 4; ++ni) acc[mi][ni] = (f32x4){0.f,0.f,0.f,0.f};

    auto mfma_step = [&](const bf16x8* bb, const f32x4* lo, const f32x4* hi) {
        bf16x8 a[4];
        #pragma unroll
        for (int mi = 0; mi < 4; ++mi) {
            union { unsigned u[4]; bf16x8 v; } cc;
            cc.u[0] = pk2bf(lo[mi][0], lo[mi][1]);
            cc.u[1] = pk2bf(lo[mi][2], lo[mi][3]);
            cc.u[2] = pk2bf(hi[mi][0], hi[mi][1]);
            cc.u[3] = pk2bf(hi[mi][2], hi[mi][3]);
            a[mi] = cc.v;
        }
        #pragma unroll
        for (int mi = 0; mi < 4; ++mi)
            #pragma unroll
            for (int ni = 0; ni < 4; ++ni)
                acc[mi][ni] = __builtin_amdgcn_mfma_f32_16x16x32_bf16(
                    bb[ni], a[mi], acc[mi][ni], 0, 0, 0);
    };

    stage(0, 0);
    stage(1, 1);
    WAIT(6); BAR();

    int br_ = 0, bw_ = 2;
    for (int s = 0; s < 6; ++s) {
        bf16x8 bb[4];
        f32x4 lo[4], hi[4];
        dsreadB(br_, bb);
        dsreadA(br_, lo, hi);
        stage(bw_, s + 2);
        mfma_step(bb, lo, hi);
        WAIT(6); BAR();
        br_ = (br_ == 2) ? 0 : br_ + 1;
        bw_ = (bw_ == 2) ? 0 : bw_ + 1;
    }
    {   // s = 6 (step 8 doesn't exist: no stage)
        bf16x8 bb[4];
        f32x4 lo[4], hi[4];
        dsreadB(br_, bb);
        dsreadA(br_, lo, hi);
        mfma_step(bb, lo, hi);
        WAIT(0); BAR();
        br_ = (br_ == 2) ? 0 : br_ + 1;
    }
    {   // s = 7
        bf16x8 bb[4];
        f32x4 lo[4], hi[4];
        dsreadB(br_, bb);
        dsreadA(br_, lo, hi);
        mfma_step(bb, lo, hi);
    }

    // epilogue: store s covers true cols wc*64 + s*32 + g*8 + [0,8)
    #pragma unroll
    for (int s = 0; s < 2; ++s) {
        int colb = wc*64 + s*32 + g*8;
        float4 b0 = *reinterpret_cast<const float4*>(bias + colb);
        float4 b1 = *reinterpret_cast<const float4*>(bias + colb + 4);
        #pragma unroll
        for (int mi = 0; mi < 4; ++mi) {
            int m = t0 + mi*16 + l15;
            float y0 = acc[mi][2*s  ][0] + b0.x;
            float y1 = acc[mi][2*s  ][1] + b0.y;
            float y2 = acc[mi][2*s  ][2] + b0.z;
            float y3 = acc[mi][2*s  ][3] + b0.w;
            float y4 = acc[mi][2*s+1][0] + b1.x;
            float y5 = acc[mi][2*s+1][1] + b1.y;
            float y6 = acc[mi][2*s+1][2] + b1.z;
            float y7 = acc[mi][2*s+1][3] + b1.w;
            if (doabs) {
                y0 = fabsf(y0); y1 = fabsf(y1); y2 = fabsf(y2); y3 = fabsf(y3);
                y4 = fabsf(y4); y5 = fabsf(y5); y6 = fabsf(y6); y7 = fabsf(y7);
            }
            uint4 pk;
            pk.x = pk2bf(y0, y1); pk.y = pk2bf(y2, y3);
            pk.z = pk2bf(y4, y5); pk.w = pk2bf(y6, y7);
            *reinterpret_cast<uint4*>(Y + (size_t)m*256 + colb) = pk;
        }
    }
}

// ---------------- pools: partial softmax pooling ----------------------------
// mode 0: coef = wqa*SCALE. mode 1: compute gq from part_in, coef = gq*wka*SCALE.
__global__ __launch_bounds__(512) void pool_partial(
    const unsigned short* __restrict__ data,
    const float* __restrict__ wqa, const float* __restrict__ wka,
    const float* __restrict__ part_in, float* __restrict__ part_out, int mode)
{
    const int bh = blockIdx.x, ch = blockIdx.y;
    const int b = bh >> 3, h = bh & 7;
    const int tid = threadIdx.x;

    __shared__ float coef[32];
    __shared__ float s_red[8];
    __shared__ float a_red[8][32];

    if (tid < 32) {
        float cc;
        if (mode == 0) cc = wqa[tid];
        else {
            float num = 0.f, den = 0.f;
            #pragma unroll
            for (int c = 0; c < 8; ++c) {
                num += part_in[(size_t)(bh*8 + c)*40 + tid];
                den += part_in[(size_t)(bh*8 + c)*40 + 32];
            }
            cc = (num / den) * wka[tid];
        }
        coef[tid] = cc * SCALE_F;
    }
    __syncthreads();
    float cf[32];
    #pragma unroll
    for (int d = 0; d < 32; ++d) cf[d] = coef[d];

    float s = 0.f;
    float acc[32];
    #pragma unroll
    for (int d = 0; d < 32; ++d) acc[d] = 0.f;

    const unsigned short* base = data + (size_t)b * N_ * 256 + h * 32;
    for (int n = ch*2048 + tid; n < (ch + 1)*2048; n += 512) {
        const uint4* p = reinterpret_cast<const uint4*>(base + (size_t)n * 256);
        float qv[32];
        #pragma unroll
        for (int gg = 0; gg < 4; ++gg) {
            uint4 r = p[gg];
            unsigned w0 = r.x, w1 = r.y, w2 = r.z, w3 = r.w;
            qv[gg*8+0] = __uint_as_float(w0 << 16);
            qv[gg*8+1] = __uint_as_float(w0 & 0xffff0000u);
            qv[gg*8+2] = __uint_as_float(w1 << 16);
            qv[gg*8+3] = __uint_as_float(w1 & 0xffff0000u);
            qv[gg*8+4] = __uint_as_float(w2 << 16);
            qv[gg*8+5] = __uint_as_float(w2 & 0xffff0000u);
            qv[gg*8+6] = __uint_as_float(w3 << 16);
            qv[gg*8+7] = __uint_as_float(w3 & 0xffff0000u);
        }
        float l = 0.f;
        #pragma unroll
        for (int d = 0; d < 32; ++d) l = fmaf(qv[d], cf[d], l);
        float e = expf(l);
        s += e;
        #pragma unroll
        for (int d = 0; d < 32; ++d) acc[d] = fmaf(e, qv[d], acc[d]);
    }

    #pragma unroll
    for (int off = 1; off < 64; off <<= 1) {
        s += __shfl_xor(s, off);
        #pragma unroll
        for (int d = 0; d < 32; ++d) acc[d] += __shfl_xor(acc[d], off);
    }
    const int wave = tid >> 6, lane = tid & 63;
    if (lane == 0) {
        s_red[wave] = s;
        #pragma unroll
        for (int d = 0; d < 32; ++d) a_red[wave][d] = acc[d];
    }
    __syncthreads();
    if (tid < 32) {
        float num = 0.f, den = 0.f;
        #pragma unroll
        for (int w2 = 0; w2 < 8; ++w2) { num += a_red[w2][tid]; den += s_red[w2]; }
        part_out[(size_t)(bh*8 + ch)*40 + tid] = num;
        if (tid == 0) part_out[(size_t)(bh*8 + ch)*40 + 32] = den;
    }
}

// ---------------- Wcat_t[b][n][k] bf16 (gk computed inline from part_k) -----
__global__ __launch_bounds__(256) void build_wcat_t(
    const float* __restrict__ part_k, const float* __restrict__ S1t,
    const float* __restrict__ Wout, unsigned short* __restrict__ Wcat_t)
{
    const int b = blockIdx.x, n = blockIdx.y, k = threadIdx.x;
    const int h = k >> 5, d = k & 31;
    float num = 0.f, den = 0.f;
    #pragma unroll
    for (int c = 0; c < 8; ++c) {
        num += part_k[(size_t)((b*8 + h)*8 + c)*40 + d];
        den += part_k[(size_t)((b*8 + h)*8 + c)*40 + 32];
    }
    const float gkv = num / den;
    unsigned short* dst = Wcat_t + (size_t)(b*256 + n) * 512;
    dst[k]       = f2bf(gkv * S1t[(size_t)n*256 + k]);
    dst[k + 256] = f2bf(Wout[(size_t)k*256 + n]);
}

// ---------------- K4: out = [v|q] @ Wcat_t[b]^T + cvec, A+B via gl_lds ------
// grid (1024), 256 thr / 4 waves. Tile 64 M x 256 N, K=512, BK=32, 16 steps.
__global__ __launch_bounds__(256) void out_mfma(
    const unsigned short* __restrict__ v_bf, const unsigned short* __restrict__ q_bf,
    const unsigned short* __restrict__ Wcat_t, const float* __restrict__ cvec,
    float* __restrict__ out)
{
    __shared__ __align__(16) unsigned short As[3][64*32];   // 3 x 4KB
    __shared__ __align__(16) unsigned short Bs[3][256*32];  // 3 x 16KB

    const int tid = threadIdx.x;
    const int t0 = blockIdx.x * 64;
    const int b  = t0 >> 14;
    const unsigned short* Wb = Wcat_t + (size_t)b * 256 * 512;

    const int wid = tid >> 6, lane = tid & 63;
    const int l15 = lane & 15, g = lane >> 4, wc = wid;

    const int sr = wid*16 + (lane >> 2);
    const int stc = (lane & 3) ^ (sr & 3) ^ ((sr >> 2) & 3);
    auto stage = [&](int buf, int step) {
        const int k0 = step * 32;
        #pragma unroll
        for (int j = 0; j < 4; ++j) {
            int n = wid*64 + j*16 + (lane >> 2);
            int cs = (lane & 3) ^ (n & 3) ^ ((n >> 2) & 3);
            gl_lds16(Wb + (size_t)n*512 + k0 + cs*8,
                     &Bs[buf][(wid*64 + j*16)*32]);
        }
        const unsigned short* src = (k0 < 256) ? v_bf : q_bf;
        const int ks = k0 & 255;
        gl_lds16(src + (size_t)(t0 + sr)*256 + ks + stc*8, &As[buf][wid*512]);
    };

    f32x4 acc[4][4];
    #pragma unroll
    for (int mi = 0; mi < 4; ++mi)
        #pragma unroll
        for (int ni = 0; ni < 4; ++ni) acc[mi][ni] = (f32x4){0.f,0.f,0.f,0.f};

    auto step_body = [&](int buf) {
        bf16x8 bb[4], a[4];
        #pragma unroll
        for (int ni = 0; ni < 4; ++ni) {
            int n2 = wc*64 + ni*16 + l15;
            int slot = g ^ (n2 & 3) ^ ((n2 >> 2) & 3);
            bb[ni] = *reinterpret_cast<const bf16x8*>(&Bs[buf][n2*32 + slot*8]);
        }
        #pragma unroll
        for (int mi = 0; mi < 4; ++mi) {
            int m = mi*16 + l15;
            int cc = g ^ (m & 3) ^ ((m >> 2) & 3);
            a[mi] = *reinterpret_cast<const bf16x8*>(&As[buf][m*32 + cc*8]);
        }
        #pragma unroll
        for (int mi = 0; mi < 4; ++mi)
            #pragma unroll
            for (int ni = 0; ni < 4; ++ni)
                acc[mi][ni] = __builtin_amdgcn_mfma_f32_16x16x32_bf16(
                    bb[ni], a[mi], acc[mi][ni], 0, 0, 0);
    };

    stage(0, 0);
    stage(1, 1);
    WAIT(5); BAR();

    int br_ = 0, bw_ = 2;
    for (int s = 0; s < 14; ++s) {
        stage(bw_, s + 2);
        step_body(br_);
        WAIT(5); BAR();
        br_ = (br_ == 2) ? 0 : br_ + 1;
        bw_ = (bw_ == 2) ? 0 : bw_ + 1;
    }
    {   // s = 14
        step_body(br_);
        WAIT(0); BAR();
        br_ = (br_ == 2) ? 0 : br_ + 1;
    }
    step_body(br_);   // s = 15

    #pragma unroll
    for (int ni = 0; ni < 4; ++ni) {
        int colb = wc*64 + ni*16 + g*4;
        float4 cv = *reinterpret_cast<const float4*>(cvec + colb);
        #pragma unroll
        for (int mi = 0; mi < 4; ++mi) {
            int m = t0 + mi*16 + l15;
            float4 o;
            o.x = acc[mi][ni][0] + cv.x;
            o.y = acc[mi][ni][1] + cv.y;
            o.z = acc[mi][ni][2] + cv.z;
            o.w = acc[mi][ni][3] + cv.w;
            *reinterpret_cast<float4*>(out + (size_t)m*256 + colb) = o;
        }
    }
}

extern "C" void kernel_launch(void* const* d_in, const int* in_sizes, int n_in,
                              void* d_out, int out_size, void* d_ws, size_t ws_size,
                              hipStream_t stream)
{
    const float* states   = (const float*)d_in[0];
    const float* agent_qs = (const float*)d_in[1];
    const float* obs      = (const float*)d_in[2];
    const float* Wq   = (const float*)d_in[3];
    const float* bq   = (const float*)d_in[4];
    const float* Wk   = (const float*)d_in[5];
    const float* bk   = (const float*)d_in[6];
    const float* Wv   = (const float*)d_in[7];
    const float* bv   = (const float*)d_in[8];
    const float* wq_attn = (const float*)d_in[9];
    const float* wk_attn = (const float*)d_in[10];
    const float* Wr   = (const float*)d_in[11];
    const float* br   = (const float*)d_in[12];
    const float* Wout = (const float*)d_in[13];
    const float* bout = (const float*)d_in[14];
    float* out = (float*)d_out;

    char* w = (char*)d_ws;
    unsigned short* q_bf = (unsigned short*)w; w += (size_t)T_ * 256 * 2;
    unsigned short* k_bf = (unsigned short*)w; w += (size_t)T_ * 256 * 2;
    unsigned short* v_bf = (unsigned short*)w; w += (size_t)T_ * 256 * 2;
    unsigned short* Wt_bf   = (unsigned short*)w; w += (size_t)3 * 65536 * 2;
    unsigned short* Wcat_t  = (unsigned short*)w; w += (size_t)4 * 256 * 512 * 2;
    float* part_q = (float*)w; w += (size_t)256 * 40 * sizeof(float);
    float* part_k = (float*)w; w += (size_t)256 * 40 * sizeof(float);
    float* S1t  = (float*)w; w += (size_t)256 * 256 * sizeof(float);
    float* cvec = (float*)w; w += 256 * sizeof(float);

    prep_all<<<dim3(260), 256, 0, stream>>>(Wq, Wk, Wv, Wt_bf,
                                            Wr, br, Wout, bout, S1t, cvec);
    proj_mfma<<<dim3(1024, 3), 256, 0, stream>>>(
        states, agent_qs, obs, Wt_bf, bq, bk, bv, q_bf, k_bf, v_bf);
    pool_partial<<<dim3(32, 8), 512, 0, stream>>>(q_bf, wq_attn, wk_attn,
                                                  part_q, part_q, 0);
    pool_partial<<<dim3(32, 8), 512, 0, stream>>>(k_bf, wq_attn, wk_attn,
                                                  part_q, part_k, 1);
    build_wcat_t<<<dim3(4, 256), 256, 0, stream>>>(part_k, S1t, Wout, Wcat_t);
    out_mfma<<<dim3(1024), 256, 0, stream>>>(v_bf, q_bf, Wcat_t, cvec, out);
}